// Round 8
// baseline (356.509 us; speedup 1.0000x reference)
//
#include <hip/hip_runtime.h>

#define TOTAL   160
#define NMAX    16
#define INDIM   1024
#define DIN     834
#define KPAD    864
#define GF      256
#define SS      1568
#define SPAD    1664   // 13 * 128

__constant__ int c_counts[16] = {6,14,10,8,16,12,9,11,7,13,10,10,8,12,6,8};
__constant__ int c_offs[16]   = {0,6,20,30,38,54,66,75,86,93,106,116,126,134,146,152};
__constant__ int c_t0[4] = {0, 12, 24, 36};   // s-tile ranges for upd (49 tiles of 32)
__constant__ int c_t1[4] = {12, 24, 36, 49};

using bf16x8 = __attribute__((ext_vector_type(8))) short;
using f32x4  = __attribute__((ext_vector_type(4))) float;
using us4    = __attribute__((ext_vector_type(4))) unsigned short;

__device__ inline unsigned short f2bf(float f) {
  union { float f; unsigned u; } v; v.f = f;
  const unsigned u = v.u;
  return (unsigned short)((u + 0x7FFFu + ((u >> 16) & 1u)) >> 16);
}
__device__ inline float bf2f(unsigned short h) {
  union { unsigned u; float f; } v; v.u = ((unsigned)h) << 16; return v.f;
}

// async 16B global -> LDS (wave-uniform LDS base + lane*16)
__device__ inline void gload_lds16(const void* g, void* l) {
  __builtin_amdgcn_global_load_lds(
      (const __attribute__((address_space(1))) unsigned*)g,
      (__attribute__((address_space(3))) unsigned*)l, 16, 0, 0);
}

// ---------------- fused prep: Wc->bf16 | Wh->bf16 | zero flatacc ----------------
// grid 4352: [0,3456) wc, [3456,3712) Wh pack, [3712,4352) zero.
__global__ __launch_bounds__(256) void prep(const float* __restrict__ Wc,
                                            unsigned short* __restrict__ Ah,
                                            const float* __restrict__ Wh,
                                            unsigned short* __restrict__ Wh_h,
                                            float* __restrict__ flatacc) {
  const int bid = blockIdx.x, tid = threadIdx.x;
  if (bid < 3456) {
    const int idx = bid * 256 + tid;             // < 4*256*864 exactly
    const int k = idx % KPAD, gm = idx / KPAD;
    Ah[idx] = (k < DIN) ? f2bf(Wc[gm * DIN + k]) : (unsigned short)0;
  } else if (bid < 3712) {
    const int i = (bid - 3456) * 256 + tid;      // < 65536 float4 groups
    const float4 v = reinterpret_cast<const float4*>(Wh)[i];
    us4 o; o[0] = f2bf(v.x); o[1] = f2bf(v.y); o[2] = f2bf(v.z); o[3] = f2bf(v.w);
    reinterpret_cast<us4*>(Wh_h)[i] = o;
  } else {
    const int i = (bid - 3712) * 256 + tid;      // < 163840 exactly
    flatacc[i] = 0.f;
  }
}

// fm [16][834][1568] fp32 -> BhT [16][1568][864] bf16 (k-contiguous, zero-padded)
__global__ __launch_bounds__(256) void fm_to_bf16T(const float* __restrict__ fm,
                                                   unsigned short* __restrict__ BhT) {
  __shared__ float tile[32][33];
  const int b  = blockIdx.z;
  const int k0 = blockIdx.y * 32;
  const int s0 = blockIdx.x * 32;
  const int tx = threadIdx.x & 31, ty = threadIdx.x >> 5;
  const float* src = fm + (size_t)b * DIN * SS;
  #pragma unroll
  for (int r = 0; r < 4; ++r) {
    const int k = k0 + ty + r * 8;
    tile[ty + r * 8][tx] = (k < DIN) ? src[(size_t)k * SS + s0 + tx] : 0.f;
  }
  __syncthreads();
  unsigned short* dst = BhT + (size_t)b * SS * KPAD;
  #pragma unroll
  for (int r = 0; r < 4; ++r) {
    const int s = s0 + ty + r * 8;
    dst[(size_t)s * KPAD + k0 + tx] = f2bf(tile[tx][ty + r * 8]);
  }
}

// ---------------- ctx GEMM: 128(s) x 256(f) tile, global_load_lds staging ----------------
// ctxT[z][s][f] = sum_k fmT[b][s][k] * Wc[g][f][k] + b_c[g][f]
__global__ __launch_bounds__(256, 2) void ctx_mfma(const unsigned short* __restrict__ Ah,
                                                   const unsigned short* __restrict__ BhT,
                                                   const float* __restrict__ b_c,
                                                   unsigned short* __restrict__ ctxT) {
  __shared__ unsigned short As[128 * 32];   // s rows, k-contig (8 KB)
  __shared__ unsigned short Bs[256 * 32];   // f rows, k-contig (16 KB)
  const int z = blockIdx.y, g = z >> 4, b = z & 15;
  const int m0 = blockIdx.x * 128;          // s
  const int tid = threadIdx.x;
  const int wave = tid >> 6, lane = tid & 63;
  const int wm = (wave >> 1) * 64, wn = (wave & 1) * 128;
  const int quad = lane >> 4, lr = lane & 15;

  const unsigned short* Ag = BhT + (size_t)b * SS * KPAD;   // rows s (junk past SS stays in-ws)
  const unsigned short* Bg = Ah + (size_t)g * 256 * KPAD;   // all 256 f rows valid

  // A: 512 chunks (2/thread); B: 1024 chunks (4/thread). chunk c: row c>>2, ko (c&3)*8
  const int ca0 = tid, ca1 = tid + 256;
  const size_t ga0 = (size_t)(m0 + (ca0 >> 2)) * KPAD + (ca0 & 3) * 8;
  const size_t ga1 = (size_t)(m0 + (ca1 >> 2)) * KPAD + (ca1 & 3) * 8;
  size_t gb[4];
  #pragma unroll
  for (int q = 0; q < 4; ++q) {
    const int c = q * 256 + tid;
    gb[q] = (size_t)(c >> 2) * KPAD + (c & 3) * 8;
  }

  f32x4 acc[4][8];
  #pragma unroll
  for (int i = 0; i < 4; ++i)
    #pragma unroll
    for (int j = 0; j < 8; ++j) acc[i][j] = (f32x4){0.f, 0.f, 0.f, 0.f};

  for (int kt = 0; kt < 27; ++kt) {
    const int k0 = kt * 32;
    __syncthreads();
    gload_lds16(Ag + ga0 + k0, &As[ca0 * 8]);
    gload_lds16(Ag + ga1 + k0, &As[ca1 * 8]);
    #pragma unroll
    for (int q = 0; q < 4; ++q)
      gload_lds16(Bg + gb[q] + k0, &Bs[(q * 256 + tid) * 8]);
    __syncthreads();
    bf16x8 af[4];
    #pragma unroll
    for (int i = 0; i < 4; ++i)
      af[i] = *reinterpret_cast<const bf16x8*>(&As[(wm + i * 16 + lr) * 32 + quad * 8]);
    #pragma unroll
    for (int j = 0; j < 8; ++j) {
      const bf16x8 bv = *reinterpret_cast<const bf16x8*>(&Bs[(wn + j * 16 + lr) * 32 + quad * 8]);
      #pragma unroll
      for (int i = 0; i < 4; ++i)
        acc[i][j] = __builtin_amdgcn_mfma_f32_16x16x32_bf16(af[i], bv, acc[i][j], 0, 0, 0);
    }
  }

  unsigned short* Cz = ctxT + (size_t)z * SPAD * GF;
  const float* bias = b_c + g * GF;
  #pragma unroll
  for (int j = 0; j < 8; ++j) {
    const int n = wn + j * 16 + lr;
    const float bv = bias[n];
    #pragma unroll
    for (int i = 0; i < 4; ++i) {
      #pragma unroll
      for (int reg = 0; reg < 4; ++reg) {
        const int m = m0 + wm + i * 16 + quad * 4 + reg;   // < SPAD always
        Cz[(size_t)m * GF + n] = f2bf(acc[i][j][reg] + bv);
      }
    }
  }
}

// ---------------- emb: bf16 MFMA with in-staging fp32->bf16 ----------------

__global__ __launch_bounds__(256) void emb_mfma(const float* __restrict__ actor,
                                                const float* __restrict__ Wa,
                                                const float* __restrict__ b_a,
                                                float* __restrict__ emb,
                                                unsigned short* __restrict__ emb_h) {
  __shared__ unsigned short As[64 * 40];
  __shared__ unsigned short Bs[64 * 40];
  const int n0 = blockIdx.x * 64, m0 = blockIdx.y * 64;
  const int tid = threadIdx.x;
  const int wave = tid >> 6, lane = tid & 63;
  const int wm = (wave >> 1) * 32, wn = (wave & 1) * 32;
  const int quad = lane >> 4, lr = lane & 15;
  const int r = tid >> 2, ko = (tid & 3) * 8;
  const bool mval = (m0 + r < TOTAL);

  f32x4 acc[2][2];
  #pragma unroll
  for (int i = 0; i < 2; ++i)
    #pragma unroll
    for (int j = 0; j < 2; ++j) acc[i][j] = (f32x4){0.f, 0.f, 0.f, 0.f};

  const float4 zf4 = {0.f, 0.f, 0.f, 0.f};
  float4 ra0, ra1, rb0, rb1;
  ra0 = mval ? *reinterpret_cast<const float4*>(actor + (size_t)(m0 + r) * INDIM + ko) : zf4;
  ra1 = mval ? *reinterpret_cast<const float4*>(actor + (size_t)(m0 + r) * INDIM + ko + 4) : zf4;
  rb0 = *reinterpret_cast<const float4*>(Wa + (size_t)(n0 + r) * INDIM + ko);
  rb1 = *reinterpret_cast<const float4*>(Wa + (size_t)(n0 + r) * INDIM + ko + 4);

  for (int kt = 0; kt < 32; ++kt) {
    __syncthreads();
    {
      us4 a0, a1, b0, b1;
      a0[0]=f2bf(ra0.x); a0[1]=f2bf(ra0.y); a0[2]=f2bf(ra0.z); a0[3]=f2bf(ra0.w);
      a1[0]=f2bf(ra1.x); a1[1]=f2bf(ra1.y); a1[2]=f2bf(ra1.z); a1[3]=f2bf(ra1.w);
      b0[0]=f2bf(rb0.x); b0[1]=f2bf(rb0.y); b0[2]=f2bf(rb0.z); b0[3]=f2bf(rb0.w);
      b1[0]=f2bf(rb1.x); b1[1]=f2bf(rb1.y); b1[2]=f2bf(rb1.z); b1[3]=f2bf(rb1.w);
      *reinterpret_cast<us4*>(&As[r * 40 + ko])     = a0;
      *reinterpret_cast<us4*>(&As[r * 40 + ko + 4]) = a1;
      *reinterpret_cast<us4*>(&Bs[r * 40 + ko])     = b0;
      *reinterpret_cast<us4*>(&Bs[r * 40 + ko + 4]) = b1;
    }
    __syncthreads();
    if (kt < 31) {
      const int k0 = (kt + 1) * 32;
      ra0 = mval ? *reinterpret_cast<const float4*>(actor + (size_t)(m0 + r) * INDIM + k0 + ko) : zf4;
      ra1 = mval ? *reinterpret_cast<const float4*>(actor + (size_t)(m0 + r) * INDIM + k0 + ko + 4) : zf4;
      rb0 = *reinterpret_cast<const float4*>(Wa + (size_t)(n0 + r) * INDIM + k0 + ko);
      rb1 = *reinterpret_cast<const float4*>(Wa + (size_t)(n0 + r) * INDIM + k0 + ko + 4);
    }
    bf16x8 af[2], bfr[2];
    #pragma unroll
    for (int i = 0; i < 2; ++i)
      af[i] = *reinterpret_cast<const bf16x8*>(&As[(wm + i * 16 + lr) * 40 + quad * 8]);
    #pragma unroll
    for (int j = 0; j < 2; ++j)
      bfr[j] = *reinterpret_cast<const bf16x8*>(&Bs[(wn + j * 16 + lr) * 40 + quad * 8]);
    #pragma unroll
    for (int i = 0; i < 2; ++i)
      #pragma unroll
      for (int j = 0; j < 2; ++j)
        acc[i][j] = __builtin_amdgcn_mfma_f32_16x16x32_bf16(af[i], bfr[j], acc[i][j], 0, 0, 0);
  }

  #pragma unroll
  for (int i = 0; i < 2; ++i) {
    #pragma unroll
    for (int reg = 0; reg < 4; ++reg) {
      const int m = m0 + wm + i * 16 + quad * 4 + reg;
      if (m >= TOTAL) continue;
      #pragma unroll
      for (int j = 0; j < 2; ++j) {
        const int n = n0 + wn + j * 16 + lr;
        const float v = acc[i][j][reg] + b_a[n];
        emb[(size_t)m * INDIM + n] = v;
        emb_h[(size_t)m * INDIM + n] = f2bf(v);
      }
    }
  }
}

// ---------------- head: out = relu((flatacc+emb) @ W_h^T), fused convert ----------------

__global__ __launch_bounds__(256) void head_mfma(const float* __restrict__ flatacc,
                                                 const float* __restrict__ emb,
                                                 const unsigned short* __restrict__ Wh_h,
                                                 float* __restrict__ out) {
  __shared__ unsigned short As[64 * 40];
  __shared__ unsigned short Bs[64 * 40];
  const int g = blockIdx.z;
  const int n0 = blockIdx.x * 64, m0 = blockIdx.y * 64;
  const int tid = threadIdx.x;
  const int wave = tid >> 6, lane = tid & 63;
  const int wm = (wave >> 1) * 32, wn = (wave & 1) * 32;
  const int quad = lane >> 4, lr = lane & 15;
  const int r = tid >> 2, ko = (tid & 3) * 8;
  const bool mval = (m0 + r < TOTAL);
  const size_t arow = (size_t)(m0 + r) * INDIM + g * GF;

  f32x4 acc[2][2];
  #pragma unroll
  for (int i = 0; i < 2; ++i)
    #pragma unroll
    for (int j = 0; j < 2; ++j) acc[i][j] = (f32x4){0.f, 0.f, 0.f, 0.f};

  const float4 zf4 = {0.f, 0.f, 0.f, 0.f};
  const uint4 zero4 = {0u, 0u, 0u, 0u};
  float4 rf0, rf1, re0, re1;
  uint4 rb;
  rf0 = mval ? *reinterpret_cast<const float4*>(flatacc + arow + ko) : zf4;
  rf1 = mval ? *reinterpret_cast<const float4*>(flatacc + arow + ko + 4) : zf4;
  re0 = mval ? *reinterpret_cast<const float4*>(emb + arow + ko) : zf4;
  re1 = mval ? *reinterpret_cast<const float4*>(emb + arow + ko + 4) : zf4;
  rb = *reinterpret_cast<const uint4*>(Wh_h + (size_t)g * GF * GF + (size_t)(n0 + r) * GF + ko);

  for (int kt = 0; kt < 8; ++kt) {
    __syncthreads();
    {
      us4 a0, a1;
      a0[0]=f2bf(rf0.x+re0.x); a0[1]=f2bf(rf0.y+re0.y); a0[2]=f2bf(rf0.z+re0.z); a0[3]=f2bf(rf0.w+re0.w);
      a1[0]=f2bf(rf1.x+re1.x); a1[1]=f2bf(rf1.y+re1.y); a1[2]=f2bf(rf1.z+re1.z); a1[3]=f2bf(rf1.w+re1.w);
      *reinterpret_cast<us4*>(&As[r * 40 + ko])     = a0;
      *reinterpret_cast<us4*>(&As[r * 40 + ko + 4]) = a1;
      *reinterpret_cast<uint4*>(&Bs[r * 40 + ko]) = rb;
    }
    __syncthreads();
    if (kt < 7) {
      const int k0 = (kt + 1) * 32;
      rf0 = mval ? *reinterpret_cast<const float4*>(flatacc + arow + k0 + ko) : zf4;
      rf1 = mval ? *reinterpret_cast<const float4*>(flatacc + arow + k0 + ko + 4) : zf4;
      re0 = mval ? *reinterpret_cast<const float4*>(emb + arow + k0 + ko) : zf4;
      re1 = mval ? *reinterpret_cast<const float4*>(emb + arow + k0 + ko + 4) : zf4;
      rb = *reinterpret_cast<const uint4*>(Wh_h + (size_t)g * GF * GF + (size_t)(n0 + r) * GF + k0 + ko);
    }
    bf16x8 af[2], bfr[2];
    #pragma unroll
    for (int i = 0; i < 2; ++i)
      af[i] = *reinterpret_cast<const bf16x8*>(&As[(wm + i * 16 + lr) * 40 + quad * 8]);
    #pragma unroll
    for (int j = 0; j < 2; ++j)
      bfr[j] = *reinterpret_cast<const bf16x8*>(&Bs[(wn + j * 16 + lr) * 40 + quad * 8]);
    #pragma unroll
    for (int i = 0; i < 2; ++i)
      #pragma unroll
      for (int j = 0; j < 2; ++j)
        acc[i][j] = __builtin_amdgcn_mfma_f32_16x16x32_bf16(af[i], bfr[j], acc[i][j], 0, 0, 0);
  }

  #pragma unroll
  for (int i = 0; i < 2; ++i) {
    #pragma unroll
    for (int reg = 0; reg < 4; ++reg) {
      const int m = m0 + wm + i * 16 + quad * 4 + reg;
      if (m >= TOTAL) continue;
      #pragma unroll
      for (int j = 0; j < 2; ++j) {
        const int n = n0 + wn + j * 16 + lr;
        out[(size_t)m * INDIM + g * GF + n] = fmaxf(acc[i][j][reg], 0.f);
      }
    }
  }
}

// ---------------- adj via MFMA: PT[z][s][n] = logits^T, partial stats ----------------

__global__ __launch_bounds__(256) void adj_mfma(const unsigned short* __restrict__ ctxT,
                                                const unsigned short* __restrict__ emb_h,
                                                float* __restrict__ PT,
                                                float* __restrict__ pstat) {
  __shared__ float redm[4][16];
  __shared__ float redl[4][16];
  const int blk = blockIdx.x, z = blockIdx.y;
  const int g = z >> 4, b = z & 15;
  const int count = c_counts[b], off = c_offs[b];
  const int tid = threadIdx.x, wave = tid >> 6, lane = tid & 63;
  const int quad = lane >> 4, lr = lane & 15;
  const int sbase = blk * 128 + wave * 32;
  const unsigned short* Az = ctxT + (size_t)z * SPAD * GF;
  const bool bvalid = (lr < count);
  const unsigned short* Brow = emb_h + (size_t)(off + (bvalid ? lr : 0)) * INDIM + (g << 8);

  f32x4 acc[2] = {(f32x4){0.f, 0.f, 0.f, 0.f}, (f32x4){0.f, 0.f, 0.f, 0.f}};
  const bf16x8 zero8 = (bf16x8)(short)0;

  #pragma unroll
  for (int kk = 0; kk < 8; ++kk) {
    const int f = kk * 32 + quad * 8;
    bf16x8 bv8 = *reinterpret_cast<const bf16x8*>(Brow + f);
    if (!bvalid) bv8 = zero8;
    #pragma unroll
    for (int i = 0; i < 2; ++i) {
      const bf16x8 av8 = *reinterpret_cast<const bf16x8*>(
          Az + (size_t)(sbase + i * 16 + lr) * GF + f);
      acc[i] = __builtin_amdgcn_mfma_f32_16x16x32_bf16(av8, bv8, acc[i], 0, 0, 0);
    }
  }

  float* PTz = PT + (size_t)z * SS * 16;
  float mx = -3.0e38f;
  #pragma unroll
  for (int i = 0; i < 2; ++i)
    #pragma unroll
    for (int reg = 0; reg < 4; ++reg) {
      const int s = sbase + i * 16 + quad * 4 + reg;
      if (s < SS) {
        PTz[s * 16 + lr] = acc[i][reg];
        mx = fmaxf(mx, acc[i][reg]);
      }
    }
  float l = 0.f;
  #pragma unroll
  for (int i = 0; i < 2; ++i)
    #pragma unroll
    for (int reg = 0; reg < 4; ++reg) {
      const int s = sbase + i * 16 + quad * 4 + reg;
      if (s < SS) l += __expf(acc[i][reg] - mx);
    }
  #pragma unroll
  for (int d = 16; d < 64; d <<= 1) {
    const float om = __shfl_xor(mx, d, 64);
    const float ol = __shfl_xor(l, d, 64);
    const float M = fmaxf(mx, om);
    l = l * __expf(mx - M) + ol * __expf(om - M);
    mx = M;
  }
  if (lane < 16) { redm[wave][lr] = mx; redl[wave][lr] = l; }
  __syncthreads();
  if (tid < 16) {
    float M = -3.0e38f;
    #pragma unroll
    for (int w = 0; w < 4; ++w) M = fmaxf(M, redm[w][tid]);
    float L = 0.f;
    #pragma unroll
    for (int w = 0; w < 4; ++w) L += redl[w][tid] * __expf(redm[w][tid] - M);
    pstat[((size_t)z * 13 + blk) * 32 + tid]      = M;
    pstat[((size_t)z * 13 + blk) * 32 + 16 + tid] = L;
  }
}

// ---------------- upd: O[n][f] += sum_s P[s][n] * ctxT[s][f], fused stat combine ----------------

__global__ __launch_bounds__(256) void upd_part(
    const unsigned short* __restrict__ ctxT, const float* __restrict__ PT,
    const float* __restrict__ pstat, float* __restrict__ flatacc)
{
  __shared__ float Bs[32][65];
  __shared__ float Ps[32][17];
  __shared__ float sm[16], sil[16];
  const int fc = blockIdx.x, sc = blockIdx.y, z = blockIdx.z;
  const int g = z >> 4, b = z & 15;
  const int count = c_counts[b], off = c_offs[b];
  const int f0 = fc << 6;
  const int t0 = c_t0[sc], t1 = c_t1[sc];
  const unsigned short* Az = ctxT + (size_t)z * SPAD * GF;
  const float* PTz = PT + (size_t)z * SS * 16;
  const int tid = threadIdx.x;
  if (tid < 16) {
    float M = -3.0e38f;
    #pragma unroll
    for (int cc = 0; cc < 13; ++cc)
      M = fmaxf(M, pstat[((size_t)z * 13 + cc) * 32 + tid]);
    float L = 0.f;
    #pragma unroll
    for (int cc = 0; cc < 13; ++cc)
      L += pstat[((size_t)z * 13 + cc) * 32 + 16 + tid] *
           __expf(pstat[((size_t)z * 13 + cc) * 32 + tid] - M);
    sm[tid] = M;
    sil[tid] = 1.0f / L;
  }
  __syncthreads();

  const int TX = tid & 63, TY = tid >> 6;
  float o[4] = {};
  for (int t = t0; t < t1; ++t) {
    const int s0 = t * 32;
    #pragma unroll
    for (int q = 0; q < 2; ++q) {
      const int idx = q * 256 + tid;
      const int nn = idx & 15, ss = idx >> 4;
      Ps[ss][nn] = __expf(PTz[(s0 + ss) * 16 + nn] - sm[nn]) * sil[nn];
    }
    #pragma unroll
    for (int q = 0; q < 4; ++q) {
      const int idx = q * 256 + tid;
      const int f2 = idx & 31, ss = idx >> 5;
      const unsigned pair = *reinterpret_cast<const unsigned*>(
          Az + (size_t)(s0 + ss) * GF + f0 + f2 * 2);
      Bs[ss][f2 * 2]     = bf2f((unsigned short)(pair & 0xFFFF));
      Bs[ss][f2 * 2 + 1] = bf2f((unsigned short)(pair >> 16));
    }
    __syncthreads();
    #pragma unroll
    for (int k = 0; k < 32; ++k) {
      const float bv = Bs[k][TX];
      #pragma unroll
      for (int i = 0; i < 4; ++i)
        o[i] = fmaf(Ps[k][(TY << 2) + i], bv, o[i]);
    }
    __syncthreads();
  }
  #pragma unroll
  for (int i = 0; i < 4; ++i) {
    const int n = (TY << 2) + i;
    if (n < count) {
      const int t = off + n;
      const int col = (g << 8) + f0 + TX;
      atomicAdd(&flatacc[t * INDIM + col], o[i]);
    }
  }
}

extern "C" void kernel_launch(void* const* d_in, const int* in_sizes, int n_in,
                              void* d_out, int out_size, void* d_ws, size_t ws_size,
                              hipStream_t stream) {
  (void)in_sizes; (void)n_in; (void)out_size; (void)ws_size;
  const float* actor = (const float*)d_in[0];
  const float* fmap  = (const float*)d_in[1];
  const float* W_a   = (const float*)d_in[2];
  const float* b_a   = (const float*)d_in[3];
  const float* W_c   = (const float*)d_in[4];
  const float* b_c   = (const float*)d_in[5];
  const float* W_h   = (const float*)d_in[6];
  float* out = (float*)d_out;
  char* ws = (char*)d_ws;

  float* emb             = (float*)(ws);                        // 655,360 B
  float* flatacc         = (float*)(ws + 655360);               // 655,360 B
  unsigned short* emb_h  = (unsigned short*)(ws + 1310720);     // 327,680 B
  float* mstat_unused    = (float*)(ws + 1638400);              // (spare)
  float* PT              = (float*)(ws + 1974272);              // 6,422,528 B
  unsigned short* ctxT   = (unsigned short*)(ws + 8396800);     // 54,525,952 B
  unsigned short* Ah     = (unsigned short*)(ws + 62922752);    // 1,769,472 B
  float* pstat           = (float*)(ws + 62922752);             // aliases Ah (time-disjoint)
  unsigned short* BhT    = (unsigned short*)(ws + 64692224);    // 43,352,064 B
  unsigned short* Wh_h   = (unsigned short*)(ws + 108044288);   // 524,288 B (end 108,568,576)
  (void)mstat_unused;

  // 0) fused prep (Wc->bf16, Wh->bf16, zero flatacc)
  hipLaunchKernelGGL(prep, dim3(4352), dim3(256), 0, stream, W_c, Ah, W_h, Wh_h, flatacc);
  hipLaunchKernelGGL(fm_to_bf16T, dim3(49, 27, 16), dim3(256), 0, stream, fmap, BhT);

  // 1) emb via bf16 MFMA (writes emb fp32 + emb_h bf16)
  hipLaunchKernelGGL(emb_mfma, dim3(16, 3), dim3(256), 0, stream,
                     actor, W_a, b_a, emb, emb_h);

  // 2) ctxT via bf16 MFMA, 128x256 tile
  hipLaunchKernelGGL(ctx_mfma, dim3(13, 64), dim3(256), 0, stream, Ah, BhT, b_c, ctxT);

  // 3) adj logits via MFMA -> PT + partial stats
  hipLaunchKernelGGL(adj_mfma, dim3(13, 64), dim3(256), 0, stream, ctxT, emb_h, PT, pstat);

  // 4) upd (f-split 4 x s-split 4, fused stat combine) -> atomic partial O
  hipLaunchKernelGGL(upd_part, dim3(4, 4, 64), dim3(256), 0, stream,
                     ctxT, PT, pstat, flatacc);

  // 5) out = relu((flatacc+emb) @ W_h^T), fused convert
  hipLaunchKernelGGL(head_mfma, dim3(4, 3, 4), dim3(256), 0, stream,
                     flatacc, emb, Wh_h, out);
}

// Round 9
// 355.353 us; speedup vs baseline: 1.0033x; 1.0033x over previous
//
#include <hip/hip_runtime.h>

#define TOTAL   160
#define NMAX    16
#define INDIM   1024
#define DIN     834
#define KPAD    864
#define GF      256
#define SS      1568
#define SPAD    1664   // 13 * 128

__constant__ int c_counts[16] = {6,14,10,8,16,12,9,11,7,13,10,10,8,12,6,8};
__constant__ int c_offs[16]   = {0,6,20,30,38,54,66,75,86,93,106,116,126,134,146,152};
__constant__ int c_t0[4] = {0, 12, 24, 36};   // s-tile ranges for upd (49 tiles of 32)
__constant__ int c_t1[4] = {12, 24, 36, 49};

using bf16x8 = __attribute__((ext_vector_type(8))) short;
using f32x4  = __attribute__((ext_vector_type(4))) float;
using us4    = __attribute__((ext_vector_type(4))) unsigned short;

__device__ inline unsigned short f2bf(float f) {
  union { float f; unsigned u; } v; v.f = f;
  const unsigned u = v.u;
  return (unsigned short)((u + 0x7FFFu + ((u >> 16) & 1u)) >> 16);
}
__device__ inline float bf2f(unsigned short h) {
  union { unsigned u; float f; } v; v.u = ((unsigned)h) << 16; return v.f;
}

// ---------------- fused prep: Wc->bf16 | Wh->bf16 | zero flatacc ----------------
__global__ __launch_bounds__(256) void prep(const float* __restrict__ Wc,
                                            unsigned short* __restrict__ Ah,
                                            const float* __restrict__ Wh,
                                            unsigned short* __restrict__ Wh_h,
                                            float* __restrict__ flatacc) {
  const int bid = blockIdx.x, tid = threadIdx.x;
  if (bid < 3456) {
    const int idx = bid * 256 + tid;             // < 4*256*864 exactly
    const int k = idx % KPAD, gm = idx / KPAD;
    Ah[idx] = (k < DIN) ? f2bf(Wc[gm * DIN + k]) : (unsigned short)0;
  } else if (bid < 3712) {
    const int i = (bid - 3456) * 256 + tid;      // < 65536 float4 groups
    const float4 v = reinterpret_cast<const float4*>(Wh)[i];
    us4 o; o[0] = f2bf(v.x); o[1] = f2bf(v.y); o[2] = f2bf(v.z); o[3] = f2bf(v.w);
    reinterpret_cast<us4*>(Wh_h)[i] = o;
  } else {
    const int i = (bid - 3712) * 256 + tid;      // < 163840 exactly
    flatacc[i] = 0.f;
  }
}

// fm [16][834][1568] fp32 -> BhT [16][1568][864] bf16 (k-contiguous, zero-padded)
__global__ __launch_bounds__(256) void fm_to_bf16T(const float* __restrict__ fm,
                                                   unsigned short* __restrict__ BhT) {
  __shared__ float tile[32][33];
  const int b  = blockIdx.z;
  const int k0 = blockIdx.y * 32;
  const int s0 = blockIdx.x * 32;
  const int tx = threadIdx.x & 31, ty = threadIdx.x >> 5;
  const float* src = fm + (size_t)b * DIN * SS;
  #pragma unroll
  for (int r = 0; r < 4; ++r) {
    const int k = k0 + ty + r * 8;
    tile[ty + r * 8][tx] = (k < DIN) ? src[(size_t)k * SS + s0 + tx] : 0.f;
  }
  __syncthreads();
  unsigned short* dst = BhT + (size_t)b * SS * KPAD;
  #pragma unroll
  for (int r = 0; r < 4; ++r) {
    const int s = s0 + ty + r * 8;
    dst[(size_t)s * KPAD + k0 + tx] = f2bf(tile[tx][ty + r * 8]);
  }
}

// ---------------- ctx GEMM (R6 structure): 128x128 tile, register-prefetch staging ----------------
// ctxT[z][s][f] = sum_k fmT[b][s][k] * Wc[g][f][k] + b_c[g][f]
__global__ __launch_bounds__(256, 3) void ctx_mfma(const unsigned short* __restrict__ Ah,
                                                   const unsigned short* __restrict__ BhT,
                                                   const float* __restrict__ b_c,
                                                   unsigned short* __restrict__ ctxT) {
  __shared__ unsigned short As[128 * 40];   // s rows
  __shared__ unsigned short Bs[128 * 40];   // f rows
  const int z = blockIdx.z, g = z >> 4, b = z & 15;
  const int n0 = blockIdx.x * 128;          // f
  const int m0 = blockIdx.y * 128;          // s
  const int tid = threadIdx.x;
  const int wave = tid >> 6, lane = tid & 63;
  const int wm = (wave >> 1) * 64, wn = (wave & 1) * 64;
  const int quad = lane >> 4, lr = lane & 15;

  const unsigned short* Ag = BhT + (size_t)b * SS * KPAD;                    // rows s (junk past SS stays in-ws)
  const unsigned short* Bg = Ah + (size_t)g * 256 * KPAD + (size_t)n0 * KPAD; // rows f (all valid)

  const int c0 = tid, c1 = tid + 256;
  const int r0 = c0 >> 2, ko0 = (c0 & 3) * 8;
  const int r1 = c1 >> 2, ko1 = (c1 & 3) * 8;

  f32x4 acc[4][4];
  #pragma unroll
  for (int i = 0; i < 4; ++i)
    #pragma unroll
    for (int j = 0; j < 4; ++j) acc[i][j] = (f32x4){0.f, 0.f, 0.f, 0.f};

  uint4 ra0, ra1, rb0, rb1;
  {
    ra0 = *reinterpret_cast<const uint4*>(Ag + (size_t)(m0 + r0) * KPAD + ko0);
    ra1 = *reinterpret_cast<const uint4*>(Ag + (size_t)(m0 + r1) * KPAD + ko1);
    rb0 = *reinterpret_cast<const uint4*>(Bg + (size_t)r0 * KPAD + ko0);
    rb1 = *reinterpret_cast<const uint4*>(Bg + (size_t)r1 * KPAD + ko1);
  }

  for (int kt = 0; kt < 27; ++kt) {
    __syncthreads();
    *reinterpret_cast<uint4*>(&As[r0 * 40 + ko0]) = ra0;
    *reinterpret_cast<uint4*>(&As[r1 * 40 + ko1]) = ra1;
    *reinterpret_cast<uint4*>(&Bs[r0 * 40 + ko0]) = rb0;
    *reinterpret_cast<uint4*>(&Bs[r1 * 40 + ko1]) = rb1;
    __syncthreads();
    if (kt < 26) {
      const int k0 = (kt + 1) * 32;
      ra0 = *reinterpret_cast<const uint4*>(Ag + (size_t)(m0 + r0) * KPAD + k0 + ko0);
      ra1 = *reinterpret_cast<const uint4*>(Ag + (size_t)(m0 + r1) * KPAD + k0 + ko1);
      rb0 = *reinterpret_cast<const uint4*>(Bg + (size_t)r0 * KPAD + k0 + ko0);
      rb1 = *reinterpret_cast<const uint4*>(Bg + (size_t)r1 * KPAD + k0 + ko1);
    }
    bf16x8 af[4], bfr[4];
    #pragma unroll
    for (int i = 0; i < 4; ++i)
      af[i] = *reinterpret_cast<const bf16x8*>(&As[(wm + i * 16 + lr) * 40 + quad * 8]);
    #pragma unroll
    for (int j = 0; j < 4; ++j)
      bfr[j] = *reinterpret_cast<const bf16x8*>(&Bs[(wn + j * 16 + lr) * 40 + quad * 8]);
    #pragma unroll
    for (int i = 0; i < 4; ++i)
      #pragma unroll
      for (int j = 0; j < 4; ++j)
        acc[i][j] = __builtin_amdgcn_mfma_f32_16x16x32_bf16(af[i], bfr[j], acc[i][j], 0, 0, 0);
  }

  unsigned short* Cz = ctxT + (size_t)z * SPAD * GF;
  const float* bias = b_c + g * GF;
  #pragma unroll
  for (int j = 0; j < 4; ++j) {
    const int n = n0 + wn + j * 16 + lr;
    const float bv = bias[n];
    #pragma unroll
    for (int i = 0; i < 4; ++i) {
      #pragma unroll
      for (int reg = 0; reg < 4; ++reg) {
        const int m = m0 + wm + i * 16 + quad * 4 + reg;   // < SPAD always
        Cz[(size_t)m * GF + n] = f2bf(acc[i][j][reg] + bv);
      }
    }
  }
}

// ---------------- emb: bf16 MFMA with in-staging fp32->bf16 ----------------

__global__ __launch_bounds__(256) void emb_mfma(const float* __restrict__ actor,
                                                const float* __restrict__ Wa,
                                                const float* __restrict__ b_a,
                                                float* __restrict__ emb,
                                                unsigned short* __restrict__ emb_h) {
  __shared__ unsigned short As[64 * 40];
  __shared__ unsigned short Bs[64 * 40];
  const int n0 = blockIdx.x * 64, m0 = blockIdx.y * 64;
  const int tid = threadIdx.x;
  const int wave = tid >> 6, lane = tid & 63;
  const int wm = (wave >> 1) * 32, wn = (wave & 1) * 32;
  const int quad = lane >> 4, lr = lane & 15;
  const int r = tid >> 2, ko = (tid & 3) * 8;
  const bool mval = (m0 + r < TOTAL);

  f32x4 acc[2][2];
  #pragma unroll
  for (int i = 0; i < 2; ++i)
    #pragma unroll
    for (int j = 0; j < 2; ++j) acc[i][j] = (f32x4){0.f, 0.f, 0.f, 0.f};

  const float4 zf4 = {0.f, 0.f, 0.f, 0.f};
  float4 ra0, ra1, rb0, rb1;
  ra0 = mval ? *reinterpret_cast<const float4*>(actor + (size_t)(m0 + r) * INDIM + ko) : zf4;
  ra1 = mval ? *reinterpret_cast<const float4*>(actor + (size_t)(m0 + r) * INDIM + ko + 4) : zf4;
  rb0 = *reinterpret_cast<const float4*>(Wa + (size_t)(n0 + r) * INDIM + ko);
  rb1 = *reinterpret_cast<const float4*>(Wa + (size_t)(n0 + r) * INDIM + ko + 4);

  for (int kt = 0; kt < 32; ++kt) {
    __syncthreads();
    {
      us4 a0, a1, b0, b1;
      a0[0]=f2bf(ra0.x); a0[1]=f2bf(ra0.y); a0[2]=f2bf(ra0.z); a0[3]=f2bf(ra0.w);
      a1[0]=f2bf(ra1.x); a1[1]=f2bf(ra1.y); a1[2]=f2bf(ra1.z); a1[3]=f2bf(ra1.w);
      b0[0]=f2bf(rb0.x); b0[1]=f2bf(rb0.y); b0[2]=f2bf(rb0.z); b0[3]=f2bf(rb0.w);
      b1[0]=f2bf(rb1.x); b1[1]=f2bf(rb1.y); b1[2]=f2bf(rb1.z); b1[3]=f2bf(rb1.w);
      *reinterpret_cast<us4*>(&As[r * 40 + ko])     = a0;
      *reinterpret_cast<us4*>(&As[r * 40 + ko + 4]) = a1;
      *reinterpret_cast<us4*>(&Bs[r * 40 + ko])     = b0;
      *reinterpret_cast<us4*>(&Bs[r * 40 + ko + 4]) = b1;
    }
    __syncthreads();
    if (kt < 31) {
      const int k0 = (kt + 1) * 32;
      ra0 = mval ? *reinterpret_cast<const float4*>(actor + (size_t)(m0 + r) * INDIM + k0 + ko) : zf4;
      ra1 = mval ? *reinterpret_cast<const float4*>(actor + (size_t)(m0 + r) * INDIM + k0 + ko + 4) : zf4;
      rb0 = *reinterpret_cast<const float4*>(Wa + (size_t)(n0 + r) * INDIM + k0 + ko);
      rb1 = *reinterpret_cast<const float4*>(Wa + (size_t)(n0 + r) * INDIM + k0 + ko + 4);
    }
    bf16x8 af[2], bfr[2];
    #pragma unroll
    for (int i = 0; i < 2; ++i)
      af[i] = *reinterpret_cast<const bf16x8*>(&As[(wm + i * 16 + lr) * 40 + quad * 8]);
    #pragma unroll
    for (int j = 0; j < 2; ++j)
      bfr[j] = *reinterpret_cast<const bf16x8*>(&Bs[(wn + j * 16 + lr) * 40 + quad * 8]);
    #pragma unroll
    for (int i = 0; i < 2; ++i)
      #pragma unroll
      for (int j = 0; j < 2; ++j)
        acc[i][j] = __builtin_amdgcn_mfma_f32_16x16x32_bf16(af[i], bfr[j], acc[i][j], 0, 0, 0);
  }

  #pragma unroll
  for (int i = 0; i < 2; ++i) {
    #pragma unroll
    for (int reg = 0; reg < 4; ++reg) {
      const int m = m0 + wm + i * 16 + quad * 4 + reg;
      if (m >= TOTAL) continue;
      #pragma unroll
      for (int j = 0; j < 2; ++j) {
        const int n = n0 + wn + j * 16 + lr;
        const float v = acc[i][j][reg] + b_a[n];
        emb[(size_t)m * INDIM + n] = v;
        emb_h[(size_t)m * INDIM + n] = f2bf(v);
      }
    }
  }
}

// ---------------- head: out = relu((flatacc+emb) @ W_h^T), fused convert ----------------

__global__ __launch_bounds__(256) void head_mfma(const float* __restrict__ flatacc,
                                                 const float* __restrict__ emb,
                                                 const unsigned short* __restrict__ Wh_h,
                                                 float* __restrict__ out) {
  __shared__ unsigned short As[64 * 40];
  __shared__ unsigned short Bs[64 * 40];
  const int g = blockIdx.z;
  const int n0 = blockIdx.x * 64, m0 = blockIdx.y * 64;
  const int tid = threadIdx.x;
  const int wave = tid >> 6, lane = tid & 63;
  const int wm = (wave >> 1) * 32, wn = (wave & 1) * 32;
  const int quad = lane >> 4, lr = lane & 15;
  const int r = tid >> 2, ko = (tid & 3) * 8;
  const bool mval = (m0 + r < TOTAL);
  const size_t arow = (size_t)(m0 + r) * INDIM + g * GF;

  f32x4 acc[2][2];
  #pragma unroll
  for (int i = 0; i < 2; ++i)
    #pragma unroll
    for (int j = 0; j < 2; ++j) acc[i][j] = (f32x4){0.f, 0.f, 0.f, 0.f};

  const float4 zf4 = {0.f, 0.f, 0.f, 0.f};
  float4 rf0, rf1, re0, re1;
  uint4 rb;
  rf0 = mval ? *reinterpret_cast<const float4*>(flatacc + arow + ko) : zf4;
  rf1 = mval ? *reinterpret_cast<const float4*>(flatacc + arow + ko + 4) : zf4;
  re0 = mval ? *reinterpret_cast<const float4*>(emb + arow + ko) : zf4;
  re1 = mval ? *reinterpret_cast<const float4*>(emb + arow + ko + 4) : zf4;
  rb = *reinterpret_cast<const uint4*>(Wh_h + (size_t)g * GF * GF + (size_t)(n0 + r) * GF + ko);

  for (int kt = 0; kt < 8; ++kt) {
    __syncthreads();
    {
      us4 a0, a1;
      a0[0]=f2bf(rf0.x+re0.x); a0[1]=f2bf(rf0.y+re0.y); a0[2]=f2bf(rf0.z+re0.z); a0[3]=f2bf(rf0.w+re0.w);
      a1[0]=f2bf(rf1.x+re1.x); a1[1]=f2bf(rf1.y+re1.y); a1[2]=f2bf(rf1.z+re1.z); a1[3]=f2bf(rf1.w+re1.w);
      *reinterpret_cast<us4*>(&As[r * 40 + ko])     = a0;
      *reinterpret_cast<us4*>(&As[r * 40 + ko + 4]) = a1;
      *reinterpret_cast<uint4*>(&Bs[r * 40 + ko]) = rb;
    }
    __syncthreads();
    if (kt < 7) {
      const int k0 = (kt + 1) * 32;
      rf0 = mval ? *reinterpret_cast<const float4*>(flatacc + arow + k0 + ko) : zf4;
      rf1 = mval ? *reinterpret_cast<const float4*>(flatacc + arow + k0 + ko + 4) : zf4;
      re0 = mval ? *reinterpret_cast<const float4*>(emb + arow + k0 + ko) : zf4;
      re1 = mval ? *reinterpret_cast<const float4*>(emb + arow + k0 + ko + 4) : zf4;
      rb = *reinterpret_cast<const uint4*>(Wh_h + (size_t)g * GF * GF + (size_t)(n0 + r) * GF + k0 + ko);
    }
    bf16x8 af[2], bfr[2];
    #pragma unroll
    for (int i = 0; i < 2; ++i)
      af[i] = *reinterpret_cast<const bf16x8*>(&As[(wm + i * 16 + lr) * 40 + quad * 8]);
    #pragma unroll
    for (int j = 0; j < 2; ++j)
      bfr[j] = *reinterpret_cast<const bf16x8*>(&Bs[(wn + j * 16 + lr) * 40 + quad * 8]);
    #pragma unroll
    for (int i = 0; i < 2; ++i)
      #pragma unroll
      for (int j = 0; j < 2; ++j)
        acc[i][j] = __builtin_amdgcn_mfma_f32_16x16x32_bf16(af[i], bfr[j], acc[i][j], 0, 0, 0);
  }

  #pragma unroll
  for (int i = 0; i < 2; ++i) {
    #pragma unroll
    for (int reg = 0; reg < 4; ++reg) {
      const int m = m0 + wm + i * 16 + quad * 4 + reg;
      if (m >= TOTAL) continue;
      #pragma unroll
      for (int j = 0; j < 2; ++j) {
        const int n = n0 + wn + j * 16 + lr;
        out[(size_t)m * INDIM + g * GF + n] = fmaxf(acc[i][j][reg], 0.f);
      }
    }
  }
}

// ---------------- adj via MFMA: PT[z][s][n] = logits^T, partial stats ----------------

__global__ __launch_bounds__(256) void adj_mfma(const unsigned short* __restrict__ ctxT,
                                                const unsigned short* __restrict__ emb_h,
                                                float* __restrict__ PT,
                                                float* __restrict__ pstat) {
  __shared__ float redm[4][16];
  __shared__ float redl[4][16];
  const int blk = blockIdx.x, z = blockIdx.y;
  const int g = z >> 4, b = z & 15;
  const int count = c_counts[b], off = c_offs[b];
  const int tid = threadIdx.x, wave = tid >> 6, lane = tid & 63;
  const int quad = lane >> 4, lr = lane & 15;
  const int sbase = blk * 128 + wave * 32;
  const unsigned short* Az = ctxT + (size_t)z * SPAD * GF;
  const bool bvalid = (lr < count);
  const unsigned short* Brow = emb_h + (size_t)(off + (bvalid ? lr : 0)) * INDIM + (g << 8);

  f32x4 acc[2] = {(f32x4){0.f, 0.f, 0.f, 0.f}, (f32x4){0.f, 0.f, 0.f, 0.f}};
  const bf16x8 zero8 = (bf16x8)(short)0;

  #pragma unroll
  for (int kk = 0; kk < 8; ++kk) {
    const int f = kk * 32 + quad * 8;
    bf16x8 bv8 = *reinterpret_cast<const bf16x8*>(Brow + f);
    if (!bvalid) bv8 = zero8;
    #pragma unroll
    for (int i = 0; i < 2; ++i) {
      const bf16x8 av8 = *reinterpret_cast<const bf16x8*>(
          Az + (size_t)(sbase + i * 16 + lr) * GF + f);
      acc[i] = __builtin_amdgcn_mfma_f32_16x16x32_bf16(av8, bv8, acc[i], 0, 0, 0);
    }
  }

  float* PTz = PT + (size_t)z * SS * 16;
  float mx = -3.0e38f;
  #pragma unroll
  for (int i = 0; i < 2; ++i)
    #pragma unroll
    for (int reg = 0; reg < 4; ++reg) {
      const int s = sbase + i * 16 + quad * 4 + reg;
      if (s < SS) {
        PTz[s * 16 + lr] = acc[i][reg];
        mx = fmaxf(mx, acc[i][reg]);
      }
    }
  float l = 0.f;
  #pragma unroll
  for (int i = 0; i < 2; ++i)
    #pragma unroll
    for (int reg = 0; reg < 4; ++reg) {
      const int s = sbase + i * 16 + quad * 4 + reg;
      if (s < SS) l += __expf(acc[i][reg] - mx);
    }
  #pragma unroll
  for (int d = 16; d < 64; d <<= 1) {
    const float om = __shfl_xor(mx, d, 64);
    const float ol = __shfl_xor(l, d, 64);
    const float M = fmaxf(mx, om);
    l = l * __expf(mx - M) + ol * __expf(om - M);
    mx = M;
  }
  if (lane < 16) { redm[wave][lr] = mx; redl[wave][lr] = l; }
  __syncthreads();
  if (tid < 16) {
    float M = -3.0e38f;
    #pragma unroll
    for (int w = 0; w < 4; ++w) M = fmaxf(M, redm[w][tid]);
    float L = 0.f;
    #pragma unroll
    for (int w = 0; w < 4; ++w) L += redl[w][tid] * __expf(redm[w][tid] - M);
    pstat[((size_t)z * 13 + blk) * 32 + tid]      = M;
    pstat[((size_t)z * 13 + blk) * 32 + 16 + tid] = L;
  }
}

// ---------------- upd: O[n][f] += sum_s P[s][n] * ctxT[s][f], fused stat combine ----------------

__global__ __launch_bounds__(256) void upd_part(
    const unsigned short* __restrict__ ctxT, const float* __restrict__ PT,
    const float* __restrict__ pstat, float* __restrict__ flatacc)
{
  __shared__ float Bs[32][65];
  __shared__ float Ps[32][17];
  __shared__ float sm[16], sil[16];
  const int fc = blockIdx.x, sc = blockIdx.y, z = blockIdx.z;
  const int g = z >> 4, b = z & 15;
  const int count = c_counts[b], off = c_offs[b];
  const int f0 = fc << 6;
  const int t0 = c_t0[sc], t1 = c_t1[sc];
  const unsigned short* Az = ctxT + (size_t)z * SPAD * GF;
  const float* PTz = PT + (size_t)z * SS * 16;
  const int tid = threadIdx.x;
  if (tid < 16) {
    float M = -3.0e38f;
    #pragma unroll
    for (int cc = 0; cc < 13; ++cc)
      M = fmaxf(M, pstat[((size_t)z * 13 + cc) * 32 + tid]);
    float L = 0.f;
    #pragma unroll
    for (int cc = 0; cc < 13; ++cc)
      L += pstat[((size_t)z * 13 + cc) * 32 + 16 + tid] *
           __expf(pstat[((size_t)z * 13 + cc) * 32 + tid] - M);
    sm[tid] = M;
    sil[tid] = 1.0f / L;
  }
  __syncthreads();

  const int TX = tid & 63, TY = tid >> 6;
  float o[4] = {};
  for (int t = t0; t < t1; ++t) {
    const int s0 = t * 32;
    #pragma unroll
    for (int q = 0; q < 2; ++q) {
      const int idx = q * 256 + tid;
      const int nn = idx & 15, ss = idx >> 4;
      Ps[ss][nn] = __expf(PTz[(s0 + ss) * 16 + nn] - sm[nn]) * sil[nn];
    }
    #pragma unroll
    for (int q = 0; q < 4; ++q) {
      const int idx = q * 256 + tid;
      const int f2 = idx & 31, ss = idx >> 5;
      const unsigned pair = *reinterpret_cast<const unsigned*>(
          Az + (size_t)(s0 + ss) * GF + f0 + f2 * 2);
      Bs[ss][f2 * 2]     = bf2f((unsigned short)(pair & 0xFFFF));
      Bs[ss][f2 * 2 + 1] = bf2f((unsigned short)(pair >> 16));
    }
    __syncthreads();
    #pragma unroll
    for (int k = 0; k < 32; ++k) {
      const float bv = Bs[k][TX];
      #pragma unroll
      for (int i = 0; i < 4; ++i)
        o[i] = fmaf(Ps[k][(TY << 2) + i], bv, o[i]);
    }
    __syncthreads();
  }
  #pragma unroll
  for (int i = 0; i < 4; ++i) {
    const int n = (TY << 2) + i;
    if (n < count) {
      const int t = off + n;
      const int col = (g << 8) + f0 + TX;
      atomicAdd(&flatacc[t * INDIM + col], o[i]);
    }
  }
}

extern "C" void kernel_launch(void* const* d_in, const int* in_sizes, int n_in,
                              void* d_out, int out_size, void* d_ws, size_t ws_size,
                              hipStream_t stream) {
  (void)in_sizes; (void)n_in; (void)out_size; (void)ws_size;
  const float* actor = (const float*)d_in[0];
  const float* fmap  = (const float*)d_in[1];
  const float* W_a   = (const float*)d_in[2];
  const float* b_a   = (const float*)d_in[3];
  const float* W_c   = (const float*)d_in[4];
  const float* b_c   = (const float*)d_in[5];
  const float* W_h   = (const float*)d_in[6];
  float* out = (float*)d_out;
  char* ws = (char*)d_ws;

  float* emb             = (float*)(ws);                        // 655,360 B
  float* flatacc         = (float*)(ws + 655360);               // 655,360 B
  unsigned short* emb_h  = (unsigned short*)(ws + 1310720);     // 327,680 B
  float* PT              = (float*)(ws + 1974272);              // 6,422,528 B
  unsigned short* ctxT   = (unsigned short*)(ws + 8396800);     // 54,525,952 B
  unsigned short* Ah     = (unsigned short*)(ws + 62922752);    // 1,769,472 B
  float* pstat           = (float*)(ws + 62922752);             // aliases Ah (time-disjoint)
  unsigned short* BhT    = (unsigned short*)(ws + 64692224);    // 43,352,064 B
  unsigned short* Wh_h   = (unsigned short*)(ws + 108044288);   // 524,288 B (end 108,568,576)

  // 0) fused prep (Wc->bf16, Wh->bf16, zero flatacc)
  hipLaunchKernelGGL(prep, dim3(4352), dim3(256), 0, stream, W_c, Ah, W_h, Wh_h, flatacc);
  hipLaunchKernelGGL(fm_to_bf16T, dim3(49, 27, 16), dim3(256), 0, stream, fmap, BhT);

  // 1) emb via bf16 MFMA (writes emb fp32 + emb_h bf16)
  hipLaunchKernelGGL(emb_mfma, dim3(16, 3), dim3(256), 0, stream,
                     actor, W_a, b_a, emb, emb_h);

  // 2) ctxT via bf16 MFMA, 128x128 tile (R6 structure)
  hipLaunchKernelGGL(ctx_mfma, dim3(2, 13, 64), dim3(256), 0, stream, Ah, BhT, b_c, ctxT);

  // 3) adj logits via MFMA -> PT + partial stats
  hipLaunchKernelGGL(adj_mfma, dim3(13, 64), dim3(256), 0, stream, ctxT, emb_h, PT, pstat);

  // 4) upd (f-split 4 x s-split 4, fused stat combine) -> atomic partial O
  hipLaunchKernelGGL(upd_part, dim3(4, 4, 64), dim3(256), 0, stream,
                     ctxT, PT, pstat, flatacc);

  // 5) out = relu((flatacc+emb) @ W_h^T), fused convert
  hipLaunchKernelGGL(head_mfma, dim3(4, 3, 4), dim3(256), 0, stream,
                     flatacc, emb, Wh_h, out);
}

// Round 10
// 317.829 us; speedup vs baseline: 1.1217x; 1.1181x over previous
//
#include <hip/hip_runtime.h>

#define TOTAL   160
#define NMAX    16
#define INDIM   1024
#define DIN     834
#define KPAD    864
#define GF      256
#define SS      1568
#define SPAD    1664   // 13 * 128
#define CROW    264    // ctx LDS row stride in shorts (256 + 8 pad)

__constant__ int c_counts[16] = {6,14,10,8,16,12,9,11,7,13,10,10,8,12,6,8};
__constant__ int c_offs[16]   = {0,6,20,30,38,54,66,75,86,93,106,116,126,134,146,152};
__constant__ int c_t0[4] = {0, 12, 24, 36};   // s-tile ranges (49 tiles of 32)
__constant__ int c_t1[4] = {12, 24, 36, 49};

using bf16x8 = __attribute__((ext_vector_type(8))) short;
using f32x4  = __attribute__((ext_vector_type(4))) float;
using us4    = __attribute__((ext_vector_type(4))) unsigned short;

__device__ inline unsigned short f2bf(float f) {
  union { float f; unsigned u; } v; v.f = f;
  const unsigned u = v.u;
  return (unsigned short)((u + 0x7FFFu + ((u >> 16) & 1u)) >> 16);
}
__device__ inline float bf2f(unsigned short h) {
  union { unsigned u; float f; } v; v.u = ((unsigned)h) << 16; return v.f;
}

// ---------------- fused prep: Wc->bf16 | Wh->bf16 ----------------
__global__ __launch_bounds__(256) void prep(const float* __restrict__ Wc,
                                            unsigned short* __restrict__ Ah,
                                            const float* __restrict__ Wh,
                                            unsigned short* __restrict__ Wh_h) {
  const int bid = blockIdx.x, tid = threadIdx.x;
  if (bid < 3456) {
    const int idx = bid * 256 + tid;             // < 4*256*864 exactly
    const int k = idx % KPAD, gm = idx / KPAD;
    Ah[idx] = (k < DIN) ? f2bf(Wc[gm * DIN + k]) : (unsigned short)0;
  } else {
    const int i = (bid - 3456) * 256 + tid;      // < 65536 float4 groups
    const float4 v = reinterpret_cast<const float4*>(Wh)[i];
    us4 o; o[0] = f2bf(v.x); o[1] = f2bf(v.y); o[2] = f2bf(v.z); o[3] = f2bf(v.w);
    reinterpret_cast<us4*>(Wh_h)[i] = o;
  }
}

// fm [16][834][1568] fp32 -> BhT [16][1568][864] bf16 (k-contiguous, zero-padded)
__global__ __launch_bounds__(256) void fm_to_bf16T(const float* __restrict__ fm,
                                                   unsigned short* __restrict__ BhT) {
  __shared__ float tile[32][33];
  const int b  = blockIdx.z;
  const int k0 = blockIdx.y * 32;
  const int s0 = blockIdx.x * 32;
  const int tx = threadIdx.x & 31, ty = threadIdx.x >> 5;
  const float* src = fm + (size_t)b * DIN * SS;
  #pragma unroll
  for (int r = 0; r < 4; ++r) {
    const int k = k0 + ty + r * 8;
    tile[ty + r * 8][tx] = (k < DIN) ? src[(size_t)k * SS + s0 + tx] : 0.f;
  }
  __syncthreads();
  unsigned short* dst = BhT + (size_t)b * SS * KPAD;
  #pragma unroll
  for (int r = 0; r < 4; ++r) {
    const int s = s0 + ty + r * 8;
    dst[(size_t)s * KPAD + k0 + tx] = f2bf(tile[tx][ty + r * 8]);
  }
}

// ---------------- ctx GEMM: 128x128 tile, register-prefetch staging ----------------
__global__ __launch_bounds__(256, 3) void ctx_mfma(const unsigned short* __restrict__ Ah,
                                                   const unsigned short* __restrict__ BhT,
                                                   const float* __restrict__ b_c,
                                                   unsigned short* __restrict__ ctxT) {
  __shared__ unsigned short As[128 * 40];
  __shared__ unsigned short Bs[128 * 40];
  const int z = blockIdx.z, g = z >> 4, b = z & 15;
  const int n0 = blockIdx.x * 128;
  const int m0 = blockIdx.y * 128;
  const int tid = threadIdx.x;
  const int wave = tid >> 6, lane = tid & 63;
  const int wm = (wave >> 1) * 64, wn = (wave & 1) * 64;
  const int quad = lane >> 4, lr = lane & 15;

  const unsigned short* Ag = BhT + (size_t)b * SS * KPAD;
  const unsigned short* Bg = Ah + (size_t)g * 256 * KPAD + (size_t)n0 * KPAD;

  const int c0 = tid, c1 = tid + 256;
  const int r0 = c0 >> 2, ko0 = (c0 & 3) * 8;
  const int r1 = c1 >> 2, ko1 = (c1 & 3) * 8;

  f32x4 acc[4][4];
  #pragma unroll
  for (int i = 0; i < 4; ++i)
    #pragma unroll
    for (int j = 0; j < 4; ++j) acc[i][j] = (f32x4){0.f, 0.f, 0.f, 0.f};

  uint4 ra0, ra1, rb0, rb1;
  {
    ra0 = *reinterpret_cast<const uint4*>(Ag + (size_t)(m0 + r0) * KPAD + ko0);
    ra1 = *reinterpret_cast<const uint4*>(Ag + (size_t)(m0 + r1) * KPAD + ko1);
    rb0 = *reinterpret_cast<const uint4*>(Bg + (size_t)r0 * KPAD + ko0);
    rb1 = *reinterpret_cast<const uint4*>(Bg + (size_t)r1 * KPAD + ko1);
  }

  for (int kt = 0; kt < 27; ++kt) {
    __syncthreads();
    *reinterpret_cast<uint4*>(&As[r0 * 40 + ko0]) = ra0;
    *reinterpret_cast<uint4*>(&As[r1 * 40 + ko1]) = ra1;
    *reinterpret_cast<uint4*>(&Bs[r0 * 40 + ko0]) = rb0;
    *reinterpret_cast<uint4*>(&Bs[r1 * 40 + ko1]) = rb1;
    __syncthreads();
    if (kt < 26) {
      const int k0 = (kt + 1) * 32;
      ra0 = *reinterpret_cast<const uint4*>(Ag + (size_t)(m0 + r0) * KPAD + k0 + ko0);
      ra1 = *reinterpret_cast<const uint4*>(Ag + (size_t)(m0 + r1) * KPAD + k0 + ko1);
      rb0 = *reinterpret_cast<const uint4*>(Bg + (size_t)r0 * KPAD + k0 + ko0);
      rb1 = *reinterpret_cast<const uint4*>(Bg + (size_t)r1 * KPAD + k0 + ko1);
    }
    bf16x8 af[4], bfr[4];
    #pragma unroll
    for (int i = 0; i < 4; ++i)
      af[i] = *reinterpret_cast<const bf16x8*>(&As[(wm + i * 16 + lr) * 40 + quad * 8]);
    #pragma unroll
    for (int j = 0; j < 4; ++j)
      bfr[j] = *reinterpret_cast<const bf16x8*>(&Bs[(wn + j * 16 + lr) * 40 + quad * 8]);
    #pragma unroll
    for (int i = 0; i < 4; ++i)
      #pragma unroll
      for (int j = 0; j < 4; ++j)
        acc[i][j] = __builtin_amdgcn_mfma_f32_16x16x32_bf16(af[i], bfr[j], acc[i][j], 0, 0, 0);
  }

  unsigned short* Cz = ctxT + (size_t)z * SPAD * GF;
  const float* bias = b_c + g * GF;
  #pragma unroll
  for (int j = 0; j < 4; ++j) {
    const int n = n0 + wn + j * 16 + lr;
    const float bv = bias[n];
    #pragma unroll
    for (int i = 0; i < 4; ++i) {
      #pragma unroll
      for (int reg = 0; reg < 4; ++reg) {
        const int m = m0 + wm + i * 16 + quad * 4 + reg;
        Cz[(size_t)m * GF + n] = f2bf(acc[i][j][reg] + bv);
      }
    }
  }
}

// ---------------- emb: bf16 MFMA with in-staging fp32->bf16 ----------------
__global__ __launch_bounds__(256) void emb_mfma(const float* __restrict__ actor,
                                                const float* __restrict__ Wa,
                                                const float* __restrict__ b_a,
                                                float* __restrict__ emb,
                                                unsigned short* __restrict__ emb_h) {
  __shared__ unsigned short As[64 * 40];
  __shared__ unsigned short Bs[64 * 40];
  const int n0 = blockIdx.x * 64, m0 = blockIdx.y * 64;
  const int tid = threadIdx.x;
  const int wave = tid >> 6, lane = tid & 63;
  const int wm = (wave >> 1) * 32, wn = (wave & 1) * 32;
  const int quad = lane >> 4, lr = lane & 15;
  const int r = tid >> 2, ko = (tid & 3) * 8;
  const bool mval = (m0 + r < TOTAL);

  f32x4 acc[2][2];
  #pragma unroll
  for (int i = 0; i < 2; ++i)
    #pragma unroll
    for (int j = 0; j < 2; ++j) acc[i][j] = (f32x4){0.f, 0.f, 0.f, 0.f};

  const float4 zf4 = {0.f, 0.f, 0.f, 0.f};
  float4 ra0, ra1, rb0, rb1;
  ra0 = mval ? *reinterpret_cast<const float4*>(actor + (size_t)(m0 + r) * INDIM + ko) : zf4;
  ra1 = mval ? *reinterpret_cast<const float4*>(actor + (size_t)(m0 + r) * INDIM + ko + 4) : zf4;
  rb0 = *reinterpret_cast<const float4*>(Wa + (size_t)(n0 + r) * INDIM + ko);
  rb1 = *reinterpret_cast<const float4*>(Wa + (size_t)(n0 + r) * INDIM + ko + 4);

  for (int kt = 0; kt < 32; ++kt) {
    __syncthreads();
    {
      us4 a0, a1, b0, b1;
      a0[0]=f2bf(ra0.x); a0[1]=f2bf(ra0.y); a0[2]=f2bf(ra0.z); a0[3]=f2bf(ra0.w);
      a1[0]=f2bf(ra1.x); a1[1]=f2bf(ra1.y); a1[2]=f2bf(ra1.z); a1[3]=f2bf(ra1.w);
      b0[0]=f2bf(rb0.x); b0[1]=f2bf(rb0.y); b0[2]=f2bf(rb0.z); b0[3]=f2bf(rb0.w);
      b1[0]=f2bf(rb1.x); b1[1]=f2bf(rb1.y); b1[2]=f2bf(rb1.z); b1[3]=f2bf(rb1.w);
      *reinterpret_cast<us4*>(&As[r * 40 + ko])     = a0;
      *reinterpret_cast<us4*>(&As[r * 40 + ko + 4]) = a1;
      *reinterpret_cast<us4*>(&Bs[r * 40 + ko])     = b0;
      *reinterpret_cast<us4*>(&Bs[r * 40 + ko + 4]) = b1;
    }
    __syncthreads();
    if (kt < 31) {
      const int k0 = (kt + 1) * 32;
      ra0 = mval ? *reinterpret_cast<const float4*>(actor + (size_t)(m0 + r) * INDIM + k0 + ko) : zf4;
      ra1 = mval ? *reinterpret_cast<const float4*>(actor + (size_t)(m0 + r) * INDIM + k0 + ko + 4) : zf4;
      rb0 = *reinterpret_cast<const float4*>(Wa + (size_t)(n0 + r) * INDIM + k0 + ko);
      rb1 = *reinterpret_cast<const float4*>(Wa + (size_t)(n0 + r) * INDIM + k0 + ko + 4);
    }
    bf16x8 af[2], bfr[2];
    #pragma unroll
    for (int i = 0; i < 2; ++i)
      af[i] = *reinterpret_cast<const bf16x8*>(&As[(wm + i * 16 + lr) * 40 + quad * 8]);
    #pragma unroll
    for (int j = 0; j < 2; ++j)
      bfr[j] = *reinterpret_cast<const bf16x8*>(&Bs[(wn + j * 16 + lr) * 40 + quad * 8]);
    #pragma unroll
    for (int i = 0; i < 2; ++i)
      #pragma unroll
      for (int j = 0; j < 2; ++j)
        acc[i][j] = __builtin_amdgcn_mfma_f32_16x16x32_bf16(af[i], bfr[j], acc[i][j], 0, 0, 0);
  }

  #pragma unroll
  for (int i = 0; i < 2; ++i) {
    #pragma unroll
    for (int reg = 0; reg < 4; ++reg) {
      const int m = m0 + wm + i * 16 + quad * 4 + reg;
      if (m >= TOTAL) continue;
      #pragma unroll
      for (int j = 0; j < 2; ++j) {
        const int n = n0 + wn + j * 16 + lr;
        const float v = acc[i][j][reg] + b_a[n];
        emb[(size_t)m * INDIM + n] = v;
        emb_h[(size_t)m * INDIM + n] = f2bf(v);
      }
    }
  }
}

// ---------------- fused attention: logits MFMA + online softmax + PV ----------------
// grid (4 sc, 64 z), 256 threads (4 independent waves, interleaved s-tiles).
// Writes per-(z,sc) partial O (unnormalized, at local max M) + stats (M, L).
__global__ __launch_bounds__(256) void att_part(
    const unsigned short* __restrict__ ctxT,
    const unsigned short* __restrict__ emb_h,
    float* __restrict__ Opart,     // [64*4][16][256]
    float* __restrict__ Spart)     // [64*4][32]: 16 M then 16 L
{
  __shared__ unsigned short Cs[4][32 * CROW];   // 4 x 16.9 KB ctx tiles (reused as fp32 O at merge)
  __shared__ float Ps[4][32][20];
  __shared__ float walpha[4][16];
  __shared__ float wms[4][16], wls[4][16];
  const int sc = blockIdx.x, z = blockIdx.y;
  const int g = z >> 4, b = z & 15;
  const int count = c_counts[b], off = c_offs[b];
  const int t0 = c_t0[sc], t1 = c_t1[sc];
  const int tid = threadIdx.x, wave = tid >> 6, lane = tid & 63;
  const int quad = lane >> 4, lr = lane & 15;
  const unsigned short* Az = ctxT + (size_t)z * SPAD * GF;
  const bool bvalid = (lr < count);
  const unsigned short* Brow = emb_h + (size_t)(off + (bvalid ? lr : 0)) * INDIM + (g << 8);
  unsigned short* myC = &Cs[wave][0];
  const int fbase = quad * 64 + lr * 4;
  const bf16x8 zero8 = (bf16x8)(short)0;

  float O[16][4];
  #pragma unroll
  for (int n = 0; n < 16; ++n)
    #pragma unroll
    for (int j = 0; j < 4; ++j) O[n][j] = 0.f;
  float m_run = -3.0e38f, l_run = 0.f;   // stats for n = lr (replicated across quads)

  for (int t = t0 + wave; t < t1; t += 4) {
    const int s0 = t * 32;
    // stage ctx tile [32 s][256 f] (rows padded to CROW shorts)
    #pragma unroll
    for (int q = 0; q < 16; ++q) {
      const int row = 2 * q + (lane >> 5);
      const int col = (lane & 31) * 8;
      const uint4 v = *reinterpret_cast<const uint4*>(Az + (size_t)(s0 + row) * GF + col);
      *reinterpret_cast<uint4*>(&myC[row * CROW + col]) = v;
    }
    // logits: 16x16x32 MFMA, A = ctx rows (s, f-contig), B = emb rows (n, f-contig)
    f32x4 acc[2] = {(f32x4){0.f,0.f,0.f,0.f}, (f32x4){0.f,0.f,0.f,0.f}};
    #pragma unroll
    for (int kk = 0; kk < 8; ++kk) {
      const int f = kk * 32 + quad * 8;
      bf16x8 bv8 = *reinterpret_cast<const bf16x8*>(Brow + f);
      if (!bvalid) bv8 = zero8;
      #pragma unroll
      for (int i = 0; i < 2; ++i) {
        const bf16x8 av8 = *reinterpret_cast<const bf16x8*>(&myC[(i * 16 + lr) * CROW + f]);
        acc[i] = __builtin_amdgcn_mfma_f32_16x16x32_bf16(av8, bv8, acc[i], 0, 0, 0);
      }
    }
    // tile stats: per-lane over its 8 s, then butterfly across quads (same n = lr)
    float mx = acc[0][0];
    #pragma unroll
    for (int i = 0; i < 2; ++i)
      #pragma unroll
      for (int r = 0; r < 4; ++r) mx = fmaxf(mx, acc[i][r]);
    float lsum = 0.f;
    #pragma unroll
    for (int i = 0; i < 2; ++i)
      #pragma unroll
      for (int r = 0; r < 4; ++r) lsum += __expf(acc[i][r] - mx);
    #pragma unroll
    for (int d = 16; d < 64; d <<= 1) {
      const float om = __shfl_xor(mx, d, 64);
      const float ol = __shfl_xor(lsum, d, 64);
      const float M = fmaxf(mx, om);
      lsum = lsum * __expf(mx - M) + ol * __expf(om - M);
      mx = M;
    }
    // online update for n = lr
    const float m_new = fmaxf(m_run, mx);
    const float alpha = __expf(m_run - m_new);
    const float beta  = __expf(mx - m_new);
    l_run = alpha * l_run + beta * lsum;
    m_run = m_new;
    if (lane < 16) walpha[wave][lane] = alpha;
    // write P-hat = beta[n] * exp(logit - mx) to LDS [s][n]
    #pragma unroll
    for (int i = 0; i < 2; ++i)
      #pragma unroll
      for (int r = 0; r < 4; ++r) {
        const int sl = i * 16 + quad * 4 + r;
        Ps[wave][sl][lr] = beta * __expf(acc[i][r] - mx);
      }
    // rescale O by alpha[n] (broadcast via LDS)
    float av[16];
    {
      const float4 a0 = *reinterpret_cast<const float4*>(&walpha[wave][0]);
      const float4 a1 = *reinterpret_cast<const float4*>(&walpha[wave][4]);
      const float4 a2 = *reinterpret_cast<const float4*>(&walpha[wave][8]);
      const float4 a3 = *reinterpret_cast<const float4*>(&walpha[wave][12]);
      av[0]=a0.x; av[1]=a0.y; av[2]=a0.z; av[3]=a0.w;
      av[4]=a1.x; av[5]=a1.y; av[6]=a1.z; av[7]=a1.w;
      av[8]=a2.x; av[9]=a2.y; av[10]=a2.z; av[11]=a2.w;
      av[12]=a3.x; av[13]=a3.y; av[14]=a3.z; av[15]=a3.w;
    }
    #pragma unroll
    for (int n = 0; n < 16; ++n)
      #pragma unroll
      for (int j = 0; j < 4; ++j) O[n][j] *= av[n];
    // PV: O[n][fbase+j] += sum_s P[s][n] * ctx[s][fbase+j]
    for (int s = 0; s < 32; ++s) {
      const float4 p0 = *reinterpret_cast<const float4*>(&Ps[wave][s][0]);
      const float4 p1 = *reinterpret_cast<const float4*>(&Ps[wave][s][4]);
      const float4 p2 = *reinterpret_cast<const float4*>(&Ps[wave][s][8]);
      const float4 p3 = *reinterpret_cast<const float4*>(&Ps[wave][s][12]);
      const us4 cv = *reinterpret_cast<const us4*>(&myC[s * CROW + fbase]);
      const float c0 = bf2f(cv[0]), c1 = bf2f(cv[1]), c2 = bf2f(cv[2]), c3 = bf2f(cv[3]);
      const float pn[16] = {p0.x,p0.y,p0.z,p0.w, p1.x,p1.y,p1.z,p1.w,
                            p2.x,p2.y,p2.z,p2.w, p3.x,p3.y,p3.z,p3.w};
      #pragma unroll
      for (int n = 0; n < 16; ++n) {
        O[n][0] = fmaf(pn[n], c0, O[n][0]);
        O[n][1] = fmaf(pn[n], c1, O[n][1]);
        O[n][2] = fmaf(pn[n], c2, O[n][2]);
        O[n][3] = fmaf(pn[n], c3, O[n][3]);
      }
    }
  }

  // ---- merge 4 waves ----
  if (lane < 16) { wms[wave][lane] = m_run; wls[wave][lane] = l_run; }
  __syncthreads();
  // scale own O to block max, store fp32 into this wave's Cs region
  float* Ob = reinterpret_cast<float*>(&Cs[wave][0]);   // [16][256] fp32 (16 KB <= 16.9 KB)
  #pragma unroll
  for (int n = 0; n < 16; ++n) {
    const float Mb = fmaxf(fmaxf(wms[0][n], wms[1][n]), fmaxf(wms[2][n], wms[3][n]));
    const float e = __expf(wms[wave][n] - Mb);
    #pragma unroll
    for (int j = 0; j < 4; ++j) Ob[n * 256 + fbase + j] = O[n][j] * e;
  }
  __syncthreads();
  // wave w sums n in [4w, 4w+4) across all wave regions; write partial
  float* Op = Opart + ((size_t)z * 4 + sc) * 4096;
  #pragma unroll
  for (int nn = 0; nn < 4; ++nn) {
    const int n = wave * 4 + nn;
    float4 v = {0.f, 0.f, 0.f, 0.f};
    #pragma unroll
    for (int w = 0; w < 4; ++w) {
      const float4 x = *reinterpret_cast<const float4*>(
          reinterpret_cast<const float*>(&Cs[w][0]) + n * 256 + fbase);
      v.x += x.x; v.y += x.y; v.z += x.z; v.w += x.w;
    }
    *reinterpret_cast<float4*>(Op + n * 256 + fbase) = v;
  }
  if (wave == 0 && lane < 16) {
    const int n = lane;
    const float Mb = fmaxf(fmaxf(wms[0][n], wms[1][n]), fmaxf(wms[2][n], wms[3][n]));
    float Lb = 0.f;
    #pragma unroll
    for (int w = 0; w < 4; ++w) Lb += wls[w][n] * __expf(wms[w][n] - Mb);
    Spart[((size_t)z * 4 + sc) * 32 + n]      = Mb;
    Spart[((size_t)z * 4 + sc) * 32 + 16 + n] = Lb;
  }
}

// combine 4 s-chunk partials -> flat_h = bf16(attn + emb). grid (64 z, 16 n).
__global__ __launch_bounds__(256) void att_combine(
    const float* __restrict__ Opart, const float* __restrict__ Spart,
    const float* __restrict__ emb, unsigned short* __restrict__ flat_h) {
  const int z = blockIdx.x, n = blockIdx.y;
  const int g = z >> 4, b = z & 15;
  const int count = c_counts[b], off = c_offs[b];
  if (n >= count) return;
  const int f = threadIdx.x;
  float M = -3.0e38f;
  #pragma unroll
  for (int sc = 0; sc < 4; ++sc)
    M = fmaxf(M, Spart[((size_t)z * 4 + sc) * 32 + n]);
  float L = 0.f, acc = 0.f;
  #pragma unroll
  for (int sc = 0; sc < 4; ++sc) {
    const float e = __expf(Spart[((size_t)z * 4 + sc) * 32 + n] - M);
    L += e * Spart[((size_t)z * 4 + sc) * 32 + 16 + n];
    acc += e * Opart[((size_t)z * 4 + sc) * 4096 + n * 256 + f];
  }
  const int t = off + n;
  const int col = (g << 8) + f;
  flat_h[t * INDIM + col] = f2bf(acc / L + emb[t * INDIM + col]);
}

// ---------------- head: bf16 MFMA, out = relu(flat_h @ W_h^T) ----------------
__global__ __launch_bounds__(256) void head_mfma(const unsigned short* __restrict__ flat_h,
                                                 const unsigned short* __restrict__ Wh_h,
                                                 float* __restrict__ out) {
  __shared__ unsigned short As[64 * 40];
  __shared__ unsigned short Bs[64 * 40];
  const int g = blockIdx.z;
  const int n0 = blockIdx.x * 64, m0 = blockIdx.y * 64;
  const int tid = threadIdx.x;
  const int wave = tid >> 6, lane = tid & 63;
  const int wm = (wave >> 1) * 32, wn = (wave & 1) * 32;
  const int quad = lane >> 4, lr = lane & 15;
  const int r = tid >> 2, ko = (tid & 3) * 8;

  const unsigned short* Ag = flat_h + (size_t)m0 * INDIM + g * GF;
  const unsigned short* Bg = Wh_h + (size_t)g * GF * GF + (size_t)n0 * GF;

  f32x4 acc[2][2];
  #pragma unroll
  for (int i = 0; i < 2; ++i)
    #pragma unroll
    for (int j = 0; j < 2; ++j) acc[i][j] = (f32x4){0.f, 0.f, 0.f, 0.f};

  const uint4 zero4 = {0u, 0u, 0u, 0u};
  uint4 ra, rb;
  ra = (m0 + r < TOTAL) ? *reinterpret_cast<const uint4*>(Ag + (size_t)r * INDIM + ko) : zero4;
  rb = *reinterpret_cast<const uint4*>(Bg + (size_t)r * GF + ko);

  for (int kt = 0; kt < 8; ++kt) {
    __syncthreads();
    *reinterpret_cast<uint4*>(&As[r * 40 + ko]) = ra;
    *reinterpret_cast<uint4*>(&Bs[r * 40 + ko]) = rb;
    __syncthreads();
    if (kt < 7) {
      const int k0 = (kt + 1) * 32;
      ra = (m0 + r < TOTAL) ? *reinterpret_cast<const uint4*>(Ag + (size_t)r * INDIM + k0 + ko) : zero4;
      rb = *reinterpret_cast<const uint4*>(Bg + (size_t)r * GF + k0 + ko);
    }
    bf16x8 af[2], bfr[2];
    #pragma unroll
    for (int i = 0; i < 2; ++i)
      af[i] = *reinterpret_cast<const bf16x8*>(&As[(wm + i * 16 + lr) * 40 + quad * 8]);
    #pragma unroll
    for (int j = 0; j < 2; ++j)
      bfr[j] = *reinterpret_cast<const bf16x8*>(&Bs[(wn + j * 16 + lr) * 40 + quad * 8]);
    #pragma unroll
    for (int i = 0; i < 2; ++i)
      #pragma unroll
      for (int j = 0; j < 2; ++j)
        acc[i][j] = __builtin_amdgcn_mfma_f32_16x16x32_bf16(af[i], bfr[j], acc[i][j], 0, 0, 0);
  }

  #pragma unroll
  for (int i = 0; i < 2; ++i) {
    #pragma unroll
    for (int reg = 0; reg < 4; ++reg) {
      const int m = m0 + wm + i * 16 + quad * 4 + reg;
      if (m >= TOTAL) continue;
      #pragma unroll
      for (int j = 0; j < 2; ++j) {
        const int n = n0 + wn + j * 16 + lr;
        out[(size_t)m * INDIM + g * GF + n] = fmaxf(acc[i][j][reg], 0.f);
      }
    }
  }
}

extern "C" void kernel_launch(void* const* d_in, const int* in_sizes, int n_in,
                              void* d_out, int out_size, void* d_ws, size_t ws_size,
                              hipStream_t stream) {
  (void)in_sizes; (void)n_in; (void)out_size; (void)ws_size;
  const float* actor = (const float*)d_in[0];
  const float* fmap  = (const float*)d_in[1];
  const float* W_a   = (const float*)d_in[2];
  const float* b_a   = (const float*)d_in[3];
  const float* W_c   = (const float*)d_in[4];
  const float* b_c   = (const float*)d_in[5];
  const float* W_h   = (const float*)d_in[6];
  float* out = (float*)d_out;
  char* ws = (char*)d_ws;

  float* emb             = (float*)(ws);                        // 655,360 B
  unsigned short* flat_h = (unsigned short*)(ws + 655360);      // 327,680 B
  unsigned short* emb_h  = (unsigned short*)(ws + 983040);      // 327,680 B
  float* Spart           = (float*)(ws + 1310720);              // 32,768 B
  float* Opart           = (float*)(ws + 1343488);              // 16,777,216 B
  unsigned short* ctxT   = (unsigned short*)(ws + 18120704);    // 54,525,952 B
  unsigned short* Ah     = (unsigned short*)(ws + 72646656);    // 1,769,472 B
  unsigned short* BhT    = (unsigned short*)(ws + 74416128);    // 43,352,064 B
  unsigned short* Wh_h   = (unsigned short*)(ws + 117768192);   // 524,288 B (end 118,292,480)

  // 0) prep (Wc->bf16, Wh->bf16) + fm transpose
  hipLaunchKernelGGL(prep, dim3(3712), dim3(256), 0, stream, W_c, Ah, W_h, Wh_h);
  hipLaunchKernelGGL(fm_to_bf16T, dim3(49, 27, 16), dim3(256), 0, stream, fmap, BhT);

  // 1) emb via bf16 MFMA (writes emb fp32 + emb_h bf16)
  hipLaunchKernelGGL(emb_mfma, dim3(16, 3), dim3(256), 0, stream,
                     actor, W_a, b_a, emb, emb_h);

  // 2) ctxT via bf16 MFMA, 128x128 tile
  hipLaunchKernelGGL(ctx_mfma, dim3(2, 13, 64), dim3(256), 0, stream, Ah, BhT, b_c, ctxT);

  // 3) fused attention (logits + online softmax + PV), s-split 4
  hipLaunchKernelGGL(att_part, dim3(4, 64), dim3(256), 0, stream,
                     ctxT, emb_h, Opart, Spart);

  // 3b) combine partials -> flat_h = bf16(attn + emb)
  hipLaunchKernelGGL(att_combine, dim3(64, 16), dim3(256), 0, stream,
                     Opart, Spart, emb, flat_h);

  // 4) out = relu(flat_h @ W_h^T)
  hipLaunchKernelGGL(head_mfma, dim3(4, 3, 4), dim3(256), 0, stream,
                     flat_h, Wh_h, out);
}

// Round 11
// 316.256 us; speedup vs baseline: 1.1273x; 1.0050x over previous
//
#include <hip/hip_runtime.h>

#define TOTAL   160
#define NMAX    16
#define INDIM   1024
#define DIN     834
#define KPAD    864
#define GF      256
#define SS      1568
#define SPAD    1664   // 13 * 128
#define CROW    264    // ctx LDS row stride in shorts (256 + 8 pad)

__constant__ int c_counts[16] = {6,14,10,8,16,12,9,11,7,13,10,10,8,12,6,8};
__constant__ int c_offs[16]   = {0,6,20,30,38,54,66,75,86,93,106,116,126,134,146,152};
__constant__ int c_t0[8] = {0, 6, 12, 18, 25, 31, 37, 43};   // s-tile ranges (49 tiles of 32)
__constant__ int c_t1[8] = {6, 12, 18, 25, 31, 37, 43, 49};

using bf16x8 = __attribute__((ext_vector_type(8))) short;
using f32x4  = __attribute__((ext_vector_type(4))) float;
using us4    = __attribute__((ext_vector_type(4))) unsigned short;

__device__ inline unsigned short f2bf(float f) {
  union { float f; unsigned u; } v; v.f = f;
  const unsigned u = v.u;
  return (unsigned short)((u + 0x7FFFu + ((u >> 16) & 1u)) >> 16);
}
__device__ inline float bf2f(unsigned short h) {
  union { unsigned u; float f; } v; v.u = ((unsigned)h) << 16; return v.f;
}

// ---------------- fused prep: Wc->bf16 | Wh->bf16 ----------------
__global__ __launch_bounds__(256) void prep(const float* __restrict__ Wc,
                                            unsigned short* __restrict__ Ah,
                                            const float* __restrict__ Wh,
                                            unsigned short* __restrict__ Wh_h) {
  const int bid = blockIdx.x, tid = threadIdx.x;
  if (bid < 3456) {
    const int idx = bid * 256 + tid;             // < 4*256*864 exactly
    const int k = idx % KPAD, gm = idx / KPAD;
    Ah[idx] = (k < DIN) ? f2bf(Wc[gm * DIN + k]) : (unsigned short)0;
  } else {
    const int i = (bid - 3456) * 256 + tid;      // < 65536 float4 groups
    const float4 v = reinterpret_cast<const float4*>(Wh)[i];
    us4 o; o[0] = f2bf(v.x); o[1] = f2bf(v.y); o[2] = f2bf(v.z); o[3] = f2bf(v.w);
    reinterpret_cast<us4*>(Wh_h)[i] = o;
  }
}

// fm [16][834][1568] fp32 -> BhT [16][1568][864] bf16 (k-contiguous, zero-padded)
__global__ __launch_bounds__(256) void fm_to_bf16T(const float* __restrict__ fm,
                                                   unsigned short* __restrict__ BhT) {
  __shared__ float tile[32][33];
  const int b  = blockIdx.z;
  const int k0 = blockIdx.y * 32;
  const int s0 = blockIdx.x * 32;
  const int tx = threadIdx.x & 31, ty = threadIdx.x >> 5;
  const float* src = fm + (size_t)b * DIN * SS;
  #pragma unroll
  for (int r = 0; r < 4; ++r) {
    const int k = k0 + ty + r * 8;
    tile[ty + r * 8][tx] = (k < DIN) ? src[(size_t)k * SS + s0 + tx] : 0.f;
  }
  __syncthreads();
  unsigned short* dst = BhT + (size_t)b * SS * KPAD;
  #pragma unroll
  for (int r = 0; r < 4; ++r) {
    const int s = s0 + ty + r * 8;
    dst[(size_t)s * KPAD + k0 + tx] = f2bf(tile[tx][ty + r * 8]);
  }
}

// ---------------- ctx GEMM: 128x128 tile, 2-deep register prefetch ----------------
// ctxT[z][s][f] = sum_k fmT[b][s][k] * Wc[g][f][k] + b_c[g][f]
#define CTX_STEP(RA0, RA1, RB0, RB1, KT)                                               \
  {                                                                                    \
    __syncthreads();                                                                   \
    *reinterpret_cast<uint4*>(&As[r0 * 40 + ko0]) = RA0;                               \
    *reinterpret_cast<uint4*>(&As[r1 * 40 + ko1]) = RA1;                               \
    *reinterpret_cast<uint4*>(&Bs[r0 * 40 + ko0]) = RB0;                               \
    *reinterpret_cast<uint4*>(&Bs[r1 * 40 + ko1]) = RB1;                               \
    __syncthreads();                                                                   \
    if ((KT) + 2 < 27) {                                                               \
      const int k0n = ((KT) + 2) * 32;                                                 \
      RA0 = *reinterpret_cast<const uint4*>(Ag + (size_t)(m0 + r0) * KPAD + k0n + ko0);\
      RA1 = *reinterpret_cast<const uint4*>(Ag + (size_t)(m0 + r1) * KPAD + k0n + ko1);\
      RB0 = *reinterpret_cast<const uint4*>(Bg + (size_t)r0 * KPAD + k0n + ko0);       \
      RB1 = *reinterpret_cast<const uint4*>(Bg + (size_t)r1 * KPAD + k0n + ko1);       \
    }                                                                                  \
    bf16x8 af[4], bfr[4];                                                              \
    _Pragma("unroll")                                                                  \
    for (int i = 0; i < 4; ++i)                                                        \
      af[i] = *reinterpret_cast<const bf16x8*>(&As[(wm + i * 16 + lr) * 40 + quad * 8]); \
    _Pragma("unroll")                                                                  \
    for (int j = 0; j < 4; ++j)                                                        \
      bfr[j] = *reinterpret_cast<const bf16x8*>(&Bs[(wn + j * 16 + lr) * 40 + quad * 8]); \
    _Pragma("unroll")                                                                  \
    for (int i = 0; i < 4; ++i)                                                        \
      _Pragma("unroll")                                                                \
      for (int j = 0; j < 4; ++j)                                                      \
        acc[i][j] = __builtin_amdgcn_mfma_f32_16x16x32_bf16(af[i], bfr[j], acc[i][j], 0, 0, 0); \
  }

__global__ __launch_bounds__(256, 3) void ctx_mfma(const unsigned short* __restrict__ Ah,
                                                   const unsigned short* __restrict__ BhT,
                                                   const float* __restrict__ b_c,
                                                   unsigned short* __restrict__ ctxT) {
  __shared__ unsigned short As[128 * 40];
  __shared__ unsigned short Bs[128 * 40];
  const int z = blockIdx.z, g = z >> 4, b = z & 15;
  const int n0 = blockIdx.x * 128;
  const int m0 = blockIdx.y * 128;
  const int tid = threadIdx.x;
  const int wave = tid >> 6, lane = tid & 63;
  const int wm = (wave >> 1) * 64, wn = (wave & 1) * 64;
  const int quad = lane >> 4, lr = lane & 15;

  const unsigned short* Ag = BhT + (size_t)b * SS * KPAD;
  const unsigned short* Bg = Ah + (size_t)g * 256 * KPAD + (size_t)n0 * KPAD;

  const int c0 = tid, c1 = tid + 256;
  const int r0 = c0 >> 2, ko0 = (c0 & 3) * 8;
  const int r1 = c1 >> 2, ko1 = (c1 & 3) * 8;

  f32x4 acc[4][4];
  #pragma unroll
  for (int i = 0; i < 4; ++i)
    #pragma unroll
    for (int j = 0; j < 4; ++j) acc[i][j] = (f32x4){0.f, 0.f, 0.f, 0.f};

  uint4 ra0a, ra1a, rb0a, rb1a, ra0b, ra1b, rb0b, rb1b;
  ra0a = *reinterpret_cast<const uint4*>(Ag + (size_t)(m0 + r0) * KPAD + ko0);
  ra1a = *reinterpret_cast<const uint4*>(Ag + (size_t)(m0 + r1) * KPAD + ko1);
  rb0a = *reinterpret_cast<const uint4*>(Bg + (size_t)r0 * KPAD + ko0);
  rb1a = *reinterpret_cast<const uint4*>(Bg + (size_t)r1 * KPAD + ko1);
  ra0b = *reinterpret_cast<const uint4*>(Ag + (size_t)(m0 + r0) * KPAD + 32 + ko0);
  ra1b = *reinterpret_cast<const uint4*>(Ag + (size_t)(m0 + r1) * KPAD + 32 + ko1);
  rb0b = *reinterpret_cast<const uint4*>(Bg + (size_t)r0 * KPAD + 32 + ko0);
  rb1b = *reinterpret_cast<const uint4*>(Bg + (size_t)r1 * KPAD + 32 + ko1);

  for (int kt = 0; kt < 27; kt += 2) {
    CTX_STEP(ra0a, ra1a, rb0a, rb1a, kt);
    if (kt + 1 < 27) CTX_STEP(ra0b, ra1b, rb0b, rb1b, kt + 1);
  }

  unsigned short* Cz = ctxT + (size_t)z * SPAD * GF;
  const float* bias = b_c + g * GF;
  #pragma unroll
  for (int j = 0; j < 4; ++j) {
    const int n = n0 + wn + j * 16 + lr;
    const float bv = bias[n];
    #pragma unroll
    for (int i = 0; i < 4; ++i) {
      #pragma unroll
      for (int reg = 0; reg < 4; ++reg) {
        const int m = m0 + wm + i * 16 + quad * 4 + reg;
        Cz[(size_t)m * GF + n] = f2bf(acc[i][j][reg] + bv);
      }
    }
  }
}

// ---------------- emb: bf16 MFMA with in-staging fp32->bf16 ----------------
__global__ __launch_bounds__(256) void emb_mfma(const float* __restrict__ actor,
                                                const float* __restrict__ Wa,
                                                const float* __restrict__ b_a,
                                                float* __restrict__ emb,
                                                unsigned short* __restrict__ emb_h) {
  __shared__ unsigned short As[64 * 40];
  __shared__ unsigned short Bs[64 * 40];
  const int n0 = blockIdx.x * 64, m0 = blockIdx.y * 64;
  const int tid = threadIdx.x;
  const int wave = tid >> 6, lane = tid & 63;
  const int wm = (wave >> 1) * 32, wn = (wave & 1) * 32;
  const int quad = lane >> 4, lr = lane & 15;
  const int r = tid >> 2, ko = (tid & 3) * 8;
  const bool mval = (m0 + r < TOTAL);

  f32x4 acc[2][2];
  #pragma unroll
  for (int i = 0; i < 2; ++i)
    #pragma unroll
    for (int j = 0; j < 2; ++j) acc[i][j] = (f32x4){0.f, 0.f, 0.f, 0.f};

  const float4 zf4 = {0.f, 0.f, 0.f, 0.f};
  float4 ra0, ra1, rb0, rb1;
  ra0 = mval ? *reinterpret_cast<const float4*>(actor + (size_t)(m0 + r) * INDIM + ko) : zf4;
  ra1 = mval ? *reinterpret_cast<const float4*>(actor + (size_t)(m0 + r) * INDIM + ko + 4) : zf4;
  rb0 = *reinterpret_cast<const float4*>(Wa + (size_t)(n0 + r) * INDIM + ko);
  rb1 = *reinterpret_cast<const float4*>(Wa + (size_t)(n0 + r) * INDIM + ko + 4);

  for (int kt = 0; kt < 32; ++kt) {
    __syncthreads();
    {
      us4 a0, a1, b0, b1;
      a0[0]=f2bf(ra0.x); a0[1]=f2bf(ra0.y); a0[2]=f2bf(ra0.z); a0[3]=f2bf(ra0.w);
      a1[0]=f2bf(ra1.x); a1[1]=f2bf(ra1.y); a1[2]=f2bf(ra1.z); a1[3]=f2bf(ra1.w);
      b0[0]=f2bf(rb0.x); b0[1]=f2bf(rb0.y); b0[2]=f2bf(rb0.z); b0[3]=f2bf(rb0.w);
      b1[0]=f2bf(rb1.x); b1[1]=f2bf(rb1.y); b1[2]=f2bf(rb1.z); b1[3]=f2bf(rb1.w);
      *reinterpret_cast<us4*>(&As[r * 40 + ko])     = a0;
      *reinterpret_cast<us4*>(&As[r * 40 + ko + 4]) = a1;
      *reinterpret_cast<us4*>(&Bs[r * 40 + ko])     = b0;
      *reinterpret_cast<us4*>(&Bs[r * 40 + ko + 4]) = b1;
    }
    __syncthreads();
    if (kt < 31) {
      const int k0 = (kt + 1) * 32;
      ra0 = mval ? *reinterpret_cast<const float4*>(actor + (size_t)(m0 + r) * INDIM + k0 + ko) : zf4;
      ra1 = mval ? *reinterpret_cast<const float4*>(actor + (size_t)(m0 + r) * INDIM + k0 + ko + 4) : zf4;
      rb0 = *reinterpret_cast<const float4*>(Wa + (size_t)(n0 + r) * INDIM + k0 + ko);
      rb1 = *reinterpret_cast<const float4*>(Wa + (size_t)(n0 + r) * INDIM + k0 + ko + 4);
    }
    bf16x8 af[2], bfr[2];
    #pragma unroll
    for (int i = 0; i < 2; ++i)
      af[i] = *reinterpret_cast<const bf16x8*>(&As[(wm + i * 16 + lr) * 40 + quad * 8]);
    #pragma unroll
    for (int j = 0; j < 2; ++j)
      bfr[j] = *reinterpret_cast<const bf16x8*>(&Bs[(wn + j * 16 + lr) * 40 + quad * 8]);
    #pragma unroll
    for (int i = 0; i < 2; ++i)
      #pragma unroll
      for (int j = 0; j < 2; ++j)
        acc[i][j] = __builtin_amdgcn_mfma_f32_16x16x32_bf16(af[i], bfr[j], acc[i][j], 0, 0, 0);
  }

  #pragma unroll
  for (int i = 0; i < 2; ++i) {
    #pragma unroll
    for (int reg = 0; reg < 4; ++reg) {
      const int m = m0 + wm + i * 16 + quad * 4 + reg;
      if (m >= TOTAL) continue;
      #pragma unroll
      for (int j = 0; j < 2; ++j) {
        const int n = n0 + wn + j * 16 + lr;
        const float v = acc[i][j][reg] + b_a[n];
        emb[(size_t)m * INDIM + n] = v;
        emb_h[(size_t)m * INDIM + n] = f2bf(v);
      }
    }
  }
}

// ---------------- fused attention: logits MFMA + online softmax + PV ----------------
// grid (8 sc, 64 z), 256 threads (4 waves, interleaved s-tiles).
__global__ __launch_bounds__(256) void att_part(
    const unsigned short* __restrict__ ctxT,
    const unsigned short* __restrict__ emb_h,
    float* __restrict__ Opart,     // [64*8][16][256]
    float* __restrict__ Spart)     // [64*8][32]: 16 M then 16 L
{
  __shared__ unsigned short Cs[4][32 * CROW];
  __shared__ float Ps[4][32][20];
  __shared__ float walpha[4][16];
  __shared__ float wms[4][16], wls[4][16];
  const int sc = blockIdx.x, z = blockIdx.y;
  const int g = z >> 4, b = z & 15;
  const int count = c_counts[b], off = c_offs[b];
  const int t0 = c_t0[sc], t1 = c_t1[sc];
  const int tid = threadIdx.x, wave = tid >> 6, lane = tid & 63;
  const int quad = lane >> 4, lr = lane & 15;
  const unsigned short* Az = ctxT + (size_t)z * SPAD * GF;
  const bool bvalid = (lr < count);
  const unsigned short* Brow = emb_h + (size_t)(off + (bvalid ? lr : 0)) * INDIM + (g << 8);
  unsigned short* myC = &Cs[wave][0];
  const int fbase = quad * 64 + lr * 4;
  const bf16x8 zero8 = (bf16x8)(short)0;

  float O[16][4];
  #pragma unroll
  for (int n = 0; n < 16; ++n)
    #pragma unroll
    for (int j = 0; j < 4; ++j) O[n][j] = 0.f;
  float m_run = -3.0e38f, l_run = 0.f;

  for (int t = t0 + wave; t < t1; t += 4) {
    const int s0 = t * 32;
    #pragma unroll
    for (int q = 0; q < 16; ++q) {
      const int row = 2 * q + (lane >> 5);
      const int col = (lane & 31) * 8;
      const uint4 v = *reinterpret_cast<const uint4*>(Az + (size_t)(s0 + row) * GF + col);
      *reinterpret_cast<uint4*>(&myC[row * CROW + col]) = v;
    }
    f32x4 acc[2] = {(f32x4){0.f,0.f,0.f,0.f}, (f32x4){0.f,0.f,0.f,0.f}};
    #pragma unroll
    for (int kk = 0; kk < 8; ++kk) {
      const int f = kk * 32 + quad * 8;
      bf16x8 bv8 = *reinterpret_cast<const bf16x8*>(Brow + f);
      if (!bvalid) bv8 = zero8;
      #pragma unroll
      for (int i = 0; i < 2; ++i) {
        const bf16x8 av8 = *reinterpret_cast<const bf16x8*>(&myC[(i * 16 + lr) * CROW + f]);
        acc[i] = __builtin_amdgcn_mfma_f32_16x16x32_bf16(av8, bv8, acc[i], 0, 0, 0);
      }
    }
    float mx = acc[0][0];
    #pragma unroll
    for (int i = 0; i < 2; ++i)
      #pragma unroll
      for (int r = 0; r < 4; ++r) mx = fmaxf(mx, acc[i][r]);
    float lsum = 0.f;
    #pragma unroll
    for (int i = 0; i < 2; ++i)
      #pragma unroll
      for (int r = 0; r < 4; ++r) lsum += __expf(acc[i][r] - mx);
    #pragma unroll
    for (int d = 16; d < 64; d <<= 1) {
      const float om = __shfl_xor(mx, d, 64);
      const float ol = __shfl_xor(lsum, d, 64);
      const float M = fmaxf(mx, om);
      lsum = lsum * __expf(mx - M) + ol * __expf(om - M);
      mx = M;
    }
    const float m_new = fmaxf(m_run, mx);
    const float alpha = __expf(m_run - m_new);
    const float beta  = __expf(mx - m_new);
    l_run = alpha * l_run + beta * lsum;
    m_run = m_new;
    if (lane < 16) walpha[wave][lane] = alpha;
    #pragma unroll
    for (int i = 0; i < 2; ++i)
      #pragma unroll
      for (int r = 0; r < 4; ++r) {
        const int sl = i * 16 + quad * 4 + r;
        Ps[wave][sl][lr] = beta * __expf(acc[i][r] - mx);
      }
    float av[16];
    {
      const float4 a0 = *reinterpret_cast<const float4*>(&walpha[wave][0]);
      const float4 a1 = *reinterpret_cast<const float4*>(&walpha[wave][4]);
      const float4 a2 = *reinterpret_cast<const float4*>(&walpha[wave][8]);
      const float4 a3 = *reinterpret_cast<const float4*>(&walpha[wave][12]);
      av[0]=a0.x; av[1]=a0.y; av[2]=a0.z; av[3]=a0.w;
      av[4]=a1.x; av[5]=a1.y; av[6]=a1.z; av[7]=a1.w;
      av[8]=a2.x; av[9]=a2.y; av[10]=a2.z; av[11]=a2.w;
      av[12]=a3.x; av[13]=a3.y; av[14]=a3.z; av[15]=a3.w;
    }
    #pragma unroll
    for (int n = 0; n < 16; ++n)
      #pragma unroll
      for (int j = 0; j < 4; ++j) O[n][j] *= av[n];
    for (int s = 0; s < 32; ++s) {
      const float4 p0 = *reinterpret_cast<const float4*>(&Ps[wave][s][0]);
      const float4 p1 = *reinterpret_cast<const float4*>(&Ps[wave][s][4]);
      const float4 p2 = *reinterpret_cast<const float4*>(&Ps[wave][s][8]);
      const float4 p3 = *reinterpret_cast<const float4*>(&Ps[wave][s][12]);
      const us4 cv = *reinterpret_cast<const us4*>(&myC[s * CROW + fbase]);
      const float c0 = bf2f(cv[0]), c1 = bf2f(cv[1]), c2 = bf2f(cv[2]), c3 = bf2f(cv[3]);
      const float pn[16] = {p0.x,p0.y,p0.z,p0.w, p1.x,p1.y,p1.z,p1.w,
                            p2.x,p2.y,p2.z,p2.w, p3.x,p3.y,p3.z,p3.w};
      #pragma unroll
      for (int n = 0; n < 16; ++n) {
        O[n][0] = fmaf(pn[n], c0, O[n][0]);
        O[n][1] = fmaf(pn[n], c1, O[n][1]);
        O[n][2] = fmaf(pn[n], c2, O[n][2]);
        O[n][3] = fmaf(pn[n], c3, O[n][3]);
      }
    }
  }

  // ---- merge 4 waves ----
  if (lane < 16) { wms[wave][lane] = m_run; wls[wave][lane] = l_run; }
  __syncthreads();
  float* Ob = reinterpret_cast<float*>(&Cs[wave][0]);   // [16][256] fp32
  #pragma unroll
  for (int n = 0; n < 16; ++n) {
    const float Mb = fmaxf(fmaxf(wms[0][n], wms[1][n]), fmaxf(wms[2][n], wms[3][n]));
    const float e = __expf(wms[wave][n] - Mb);
    #pragma unroll
    for (int j = 0; j < 4; ++j) Ob[n * 256 + fbase + j] = O[n][j] * e;
  }
  __syncthreads();
  float* Op = Opart + ((size_t)z * 8 + sc) * 4096;
  #pragma unroll
  for (int nn = 0; nn < 4; ++nn) {
    const int n = wave * 4 + nn;
    float4 v = {0.f, 0.f, 0.f, 0.f};
    #pragma unroll
    for (int w = 0; w < 4; ++w) {
      const float4 x = *reinterpret_cast<const float4*>(
          reinterpret_cast<const float*>(&Cs[w][0]) + n * 256 + fbase);
      v.x += x.x; v.y += x.y; v.z += x.z; v.w += x.w;
    }
    *reinterpret_cast<float4*>(Op + n * 256 + fbase) = v;
  }
  if (wave == 0 && lane < 16) {
    const int n = lane;
    const float Mb = fmaxf(fmaxf(wms[0][n], wms[1][n]), fmaxf(wms[2][n], wms[3][n]));
    float Lb = 0.f;
    #pragma unroll
    for (int w = 0; w < 4; ++w) Lb += wls[w][n] * __expf(wms[w][n] - Mb);
    Spart[((size_t)z * 8 + sc) * 32 + n]      = Mb;
    Spart[((size_t)z * 8 + sc) * 32 + 16 + n] = Lb;
  }
}

// combine 8 s-chunk partials -> flat_h = bf16(attn + emb). grid (64 z, 16 n).
__global__ __launch_bounds__(256) void att_combine(
    const float* __restrict__ Opart, const float* __restrict__ Spart,
    const float* __restrict__ emb, unsigned short* __restrict__ flat_h) {
  const int z = blockIdx.x, n = blockIdx.y;
  const int g = z >> 4, b = z & 15;
  const int count = c_counts[b], off = c_offs[b];
  if (n >= count) return;
  const int f = threadIdx.x;
  float M = -3.0e38f;
  #pragma unroll
  for (int sc = 0; sc < 8; ++sc)
    M = fmaxf(M, Spart[((size_t)z * 8 + sc) * 32 + n]);
  float L = 0.f, acc = 0.f;
  #pragma unroll
  for (int sc = 0; sc < 8; ++sc) {
    const float e = __expf(Spart[((size_t)z * 8 + sc) * 32 + n] - M);
    L += e * Spart[((size_t)z * 8 + sc) * 32 + 16 + n];
    acc += e * Opart[((size_t)z * 8 + sc) * 4096 + n * 256 + f];
  }
  const int t = off + n;
  const int col = (g << 8) + f;
  flat_h[t * INDIM + col] = f2bf(acc / L + emb[t * INDIM + col]);
}

// ---------------- head: bf16 MFMA, out = relu(flat_h @ W_h^T) ----------------
__global__ __launch_bounds__(256) void head_mfma(const unsigned short* __restrict__ flat_h,
                                                 const unsigned short* __restrict__ Wh_h,
                                                 float* __restrict__ out) {
  __shared__ unsigned short As[64 * 40];
  __shared__ unsigned short Bs[64 * 40];
  const int g = blockIdx.z;
  const int n0 = blockIdx.x * 64, m0 = blockIdx.y * 64;
  const int tid = threadIdx.x;
  const int wave = tid >> 6, lane = tid & 63;
  const int wm = (wave >> 1) * 32, wn = (wave & 1) * 32;
  const int quad = lane >> 4, lr = lane & 15;
  const int r = tid >> 2, ko = (tid & 3) * 8;

  const unsigned short* Ag = flat_h + (size_t)m0 * INDIM + g * GF;
  const unsigned short* Bg = Wh_h + (size_t)g * GF * GF + (size_t)n0 * GF;

  f32x4 acc[2][2];
  #pragma unroll
  for (int i = 0; i < 2; ++i)
    #pragma unroll
    for (int j = 0; j < 2; ++j) acc[i][j] = (f32x4){0.f, 0.f, 0.f, 0.f};

  const uint4 zero4 = {0u, 0u, 0u, 0u};
  uint4 ra, rb;
  ra = (m0 + r < TOTAL) ? *reinterpret_cast<const uint4*>(Ag + (size_t)r * INDIM + ko) : zero4;
  rb = *reinterpret_cast<const uint4*>(Bg + (size_t)r * GF + ko);

  for (int kt = 0; kt < 8; ++kt) {
    __syncthreads();
    *reinterpret_cast<uint4*>(&As[r * 40 + ko]) = ra;
    *reinterpret_cast<uint4*>(&Bs[r * 40 + ko]) = rb;
    __syncthreads();
    if (kt < 7) {
      const int k0 = (kt + 1) * 32;
      ra = (m0 + r < TOTAL) ? *reinterpret_cast<const uint4*>(Ag + (size_t)r * INDIM + k0 + ko) : zero4;
      rb = *reinterpret_cast<const uint4*>(Bg + (size_t)r * GF + k0 + ko);
    }
    bf16x8 af[2], bfr[2];
    #pragma unroll
    for (int i = 0; i < 2; ++i)
      af[i] = *reinterpret_cast<const bf16x8*>(&As[(wm + i * 16 + lr) * 40 + quad * 8]);
    #pragma unroll
    for (int j = 0; j < 2; ++j)
      bfr[j] = *reinterpret_cast<const bf16x8*>(&Bs[(wn + j * 16 + lr) * 40 + quad * 8]);
    #pragma unroll
    for (int i = 0; i < 2; ++i)
      #pragma unroll
      for (int j = 0; j < 2; ++j)
        acc[i][j] = __builtin_amdgcn_mfma_f32_16x16x32_bf16(af[i], bfr[j], acc[i][j], 0, 0, 0);
  }

  #pragma unroll
  for (int i = 0; i < 2; ++i) {
    #pragma unroll
    for (int reg = 0; reg < 4; ++reg) {
      const int m = m0 + wm + i * 16 + quad * 4 + reg;
      if (m >= TOTAL) continue;
      #pragma unroll
      for (int j = 0; j < 2; ++j) {
        const int n = n0 + wn + j * 16 + lr;
        out[(size_t)m * INDIM + g * GF + n] = fmaxf(acc[i][j][reg], 0.f);
      }
    }
  }
}

extern "C" void kernel_launch(void* const* d_in, const int* in_sizes, int n_in,
                              void* d_out, int out_size, void* d_ws, size_t ws_size,
                              hipStream_t stream) {
  (void)in_sizes; (void)n_in; (void)out_size; (void)ws_size;
  const float* actor = (const float*)d_in[0];
  const float* fmap  = (const float*)d_in[1];
  const float* W_a   = (const float*)d_in[2];
  const float* b_a   = (const float*)d_in[3];
  const float* W_c   = (const float*)d_in[4];
  const float* b_c   = (const float*)d_in[5];
  const float* W_h   = (const float*)d_in[6];
  float* out = (float*)d_out;
  char* ws = (char*)d_ws;

  float* emb             = (float*)(ws);                        // 655,360 B
  unsigned short* flat_h = (unsigned short*)(ws + 655360);      // 327,680 B
  unsigned short* emb_h  = (unsigned short*)(ws + 983040);      // 327,680 B
  float* Spart           = (float*)(ws + 1310720);              // 65,536 B
  unsigned short* ctxT   = (unsigned short*)(ws + 1376256);     // 54,525,952 B -> 55,902,208
  unsigned short* Ah     = (unsigned short*)(ws + 55902208);    // 1,769,472 B -> 57,671,680
  unsigned short* BhT    = (unsigned short*)(ws + 57671680);    // 43,352,064 B -> 101,023,744
  float* Opart           = (float*)(ws + 57671680);             // 33,554,432 B, aliases BhT (time-disjoint)
  unsigned short* Wh_h   = (unsigned short*)(ws + 101023744);   // 524,288 B (end 101,548,032)

  // 0) prep (Wc->bf16, Wh->bf16) + fm transpose
  hipLaunchKernelGGL(prep, dim3(3712), dim3(256), 0, stream, W_c, Ah, W_h, Wh_h);
  hipLaunchKernelGGL(fm_to_bf16T, dim3(49, 27, 16), dim3(256), 0, stream, fmap, BhT);

  // 1) emb via bf16 MFMA (writes emb fp32 + emb_h bf16)
  hipLaunchKernelGGL(emb_mfma, dim3(16, 3), dim3(256), 0, stream,
                     actor, W_a, b_a, emb, emb_h);

  // 2) ctxT via bf16 MFMA, 128x128 tile, 2-deep prefetch
  hipLaunchKernelGGL(ctx_mfma, dim3(2, 13, 64), dim3(256), 0, stream, Ah, BhT, b_c, ctxT);

  // 3) fused attention (logits + online softmax + PV), s-split 8
  hipLaunchKernelGGL(att_part, dim3(8, 64), dim3(256), 0, stream,
                     ctxT, emb_h, Opart, Spart);

  // 3b) combine partials -> flat_h = bf16(attn + emb)
  hipLaunchKernelGGL(att_combine, dim3(64, 16), dim3(256), 0, stream,
                     Opart, Spart, emb, flat_h);

  // 4) out = relu(flat_h @ W_h^T)
  hipLaunchKernelGGL(head_mfma, dim3(4, 3, 4), dim3(256), 0, stream,
                     flat_h, Wh_h, out);
}

// Round 12
// 282.625 us; speedup vs baseline: 1.2614x; 1.1190x over previous
//
#include <hip/hip_runtime.h>

#define TOTAL   160
#define NMAX    16
#define INDIM   1024
#define DIN     834
#define KPAD    864
#define GF      256
#define SS      1568
#define SPAD    1664   // 13 * 128
#define CROW    264    // ctx LDS row stride in shorts (256 + 8 pad)

__constant__ int c_counts[16] = {6,14,10,8,16,12,9,11,7,13,10,10,8,12,6,8};
__constant__ int c_offs[16]   = {0,6,20,30,38,54,66,75,86,93,106,116,126,134,146,152};
__constant__ int c_t0[8] = {0, 6, 12, 18, 25, 31, 37, 43};   // s-tile ranges (49 tiles of 32)
__constant__ int c_t1[8] = {6, 12, 18, 25, 31, 37, 43, 49};

using bf16x8 = __attribute__((ext_vector_type(8))) short;
using f32x4  = __attribute__((ext_vector_type(4))) float;
using us4    = __attribute__((ext_vector_type(4))) unsigned short;

__device__ inline unsigned short f2bf(float f) {
  union { float f; unsigned u; } v; v.f = f;
  const unsigned u = v.u;
  return (unsigned short)((u + 0x7FFFu + ((u >> 16) & 1u)) >> 16);
}
__device__ inline float bf2f(unsigned short h) {
  union { unsigned u; float f; } v; v.u = ((unsigned)h) << 16; return v.f;
}

// ---------------- mega-fused front end ----------------
// blocks [0,48): emb bf16 MFMA; [48,3760): Wc/Wh pack; [3760,24928): fm transpose.
__global__ __launch_bounds__(256) void prep_all(
    const float* __restrict__ actor, const float* __restrict__ Wa,
    const float* __restrict__ b_a, const float* __restrict__ Wc,
    const float* __restrict__ Wh, const float* __restrict__ fm,
    float* __restrict__ emb, unsigned short* __restrict__ emb_h,
    unsigned short* __restrict__ Ah, unsigned short* __restrict__ Wh_h,
    unsigned short* __restrict__ BhT)
{
  __shared__ float tile[32][33];
  __shared__ unsigned short As[64 * 40];
  __shared__ unsigned short Bs[64 * 40];
  const int bid = blockIdx.x, tid = threadIdx.x;

  if (bid < 48) {
    // ---- emb: emb[m][n] = sum_k actor[m][k]*Wa[n][k] + b_a[n] ----
    const int n0 = (bid & 15) * 64, m0 = (bid >> 4) * 64;
    const int wave = tid >> 6, lane = tid & 63;
    const int wm = (wave >> 1) * 32, wn = (wave & 1) * 32;
    const int quad = lane >> 4, lr = lane & 15;
    const int r = tid >> 2, ko = (tid & 3) * 8;
    const bool mval = (m0 + r < TOTAL);

    f32x4 acc[2][2];
    #pragma unroll
    for (int i = 0; i < 2; ++i)
      #pragma unroll
      for (int j = 0; j < 2; ++j) acc[i][j] = (f32x4){0.f, 0.f, 0.f, 0.f};

    const float4 zf4 = {0.f, 0.f, 0.f, 0.f};
    float4 ra0, ra1, rb0, rb1;
    ra0 = mval ? *reinterpret_cast<const float4*>(actor + (size_t)(m0 + r) * INDIM + ko) : zf4;
    ra1 = mval ? *reinterpret_cast<const float4*>(actor + (size_t)(m0 + r) * INDIM + ko + 4) : zf4;
    rb0 = *reinterpret_cast<const float4*>(Wa + (size_t)(n0 + r) * INDIM + ko);
    rb1 = *reinterpret_cast<const float4*>(Wa + (size_t)(n0 + r) * INDIM + ko + 4);

    for (int kt = 0; kt < 32; ++kt) {
      __syncthreads();
      {
        us4 a0, a1, b0, b1;
        a0[0]=f2bf(ra0.x); a0[1]=f2bf(ra0.y); a0[2]=f2bf(ra0.z); a0[3]=f2bf(ra0.w);
        a1[0]=f2bf(ra1.x); a1[1]=f2bf(ra1.y); a1[2]=f2bf(ra1.z); a1[3]=f2bf(ra1.w);
        b0[0]=f2bf(rb0.x); b0[1]=f2bf(rb0.y); b0[2]=f2bf(rb0.z); b0[3]=f2bf(rb0.w);
        b1[0]=f2bf(rb1.x); b1[1]=f2bf(rb1.y); b1[2]=f2bf(rb1.z); b1[3]=f2bf(rb1.w);
        *reinterpret_cast<us4*>(&As[r * 40 + ko])     = a0;
        *reinterpret_cast<us4*>(&As[r * 40 + ko + 4]) = a1;
        *reinterpret_cast<us4*>(&Bs[r * 40 + ko])     = b0;
        *reinterpret_cast<us4*>(&Bs[r * 40 + ko + 4]) = b1;
      }
      __syncthreads();
      if (kt < 31) {
        const int k0 = (kt + 1) * 32;
        ra0 = mval ? *reinterpret_cast<const float4*>(actor + (size_t)(m0 + r) * INDIM + k0 + ko) : zf4;
        ra1 = mval ? *reinterpret_cast<const float4*>(actor + (size_t)(m0 + r) * INDIM + k0 + ko + 4) : zf4;
        rb0 = *reinterpret_cast<const float4*>(Wa + (size_t)(n0 + r) * INDIM + k0 + ko);
        rb1 = *reinterpret_cast<const float4*>(Wa + (size_t)(n0 + r) * INDIM + k0 + ko + 4);
      }
      bf16x8 af[2], bfr[2];
      #pragma unroll
      for (int i = 0; i < 2; ++i)
        af[i] = *reinterpret_cast<const bf16x8*>(&As[(wm + i * 16 + lr) * 40 + quad * 8]);
      #pragma unroll
      for (int j = 0; j < 2; ++j)
        bfr[j] = *reinterpret_cast<const bf16x8*>(&Bs[(wn + j * 16 + lr) * 40 + quad * 8]);
      #pragma unroll
      for (int i = 0; i < 2; ++i)
        #pragma unroll
        for (int j = 0; j < 2; ++j)
          acc[i][j] = __builtin_amdgcn_mfma_f32_16x16x32_bf16(af[i], bfr[j], acc[i][j], 0, 0, 0);
    }

    #pragma unroll
    for (int i = 0; i < 2; ++i) {
      #pragma unroll
      for (int reg = 0; reg < 4; ++reg) {
        const int m = m0 + wm + i * 16 + quad * 4 + reg;
        if (m >= TOTAL) continue;
        #pragma unroll
        for (int j = 0; j < 2; ++j) {
          const int n = n0 + wn + j * 16 + lr;
          const float v = acc[i][j][reg] + b_a[n];
          emb[(size_t)m * INDIM + n] = v;
          emb_h[(size_t)m * INDIM + n] = f2bf(v);
        }
      }
    }
  } else if (bid < 3760) {
    const int pb = bid - 48;
    if (pb < 3456) {
      const int idx = pb * 256 + tid;
      const int k = idx % KPAD, gm = idx / KPAD;
      Ah[idx] = (k < DIN) ? f2bf(Wc[gm * DIN + k]) : (unsigned short)0;
    } else {
      const int i = (pb - 3456) * 256 + tid;
      const float4 v = reinterpret_cast<const float4*>(Wh)[i];
      us4 o; o[0] = f2bf(v.x); o[1] = f2bf(v.y); o[2] = f2bf(v.z); o[3] = f2bf(v.w);
      reinterpret_cast<us4*>(Wh_h)[i] = o;
    }
  } else {
    // ---- fm [16][834][1568] fp32 -> BhT [16][1568][864] bf16 ----
    const int fb = bid - 3760;
    const int sx = fb % 49, ky = (fb / 49) % 27, b = fb / (49 * 27);
    const int k0 = ky * 32, s0 = sx * 32;
    const int tx = tid & 31, ty = tid >> 5;
    const float* src = fm + (size_t)b * DIN * SS;
    #pragma unroll
    for (int r = 0; r < 4; ++r) {
      const int k = k0 + ty + r * 8;
      tile[ty + r * 8][tx] = (k < DIN) ? src[(size_t)k * SS + s0 + tx] : 0.f;
    }
    __syncthreads();
    unsigned short* dst = BhT + (size_t)b * SS * KPAD;
    #pragma unroll
    for (int r = 0; r < 4; ++r) {
      const int s = s0 + ty + r * 8;
      dst[(size_t)s * KPAD + k0 + tx] = f2bf(tile[tx][ty + r * 8]);
    }
  }
}

// ---------------- ctx GEMM: 128x128 tile, 2-deep prefetch, L2-friendly z order ----------------
// block z -> (g = z&3, b = z>>2): the 4 g's sharing one b's A-data are adjacent.
#define CTX_STEP(RA0, RA1, RB0, RB1, KT)                                               \
  {                                                                                    \
    __syncthreads();                                                                   \
    *reinterpret_cast<uint4*>(&As[r0 * 40 + ko0]) = RA0;                               \
    *reinterpret_cast<uint4*>(&As[r1 * 40 + ko1]) = RA1;                               \
    *reinterpret_cast<uint4*>(&Bs[r0 * 40 + ko0]) = RB0;                               \
    *reinterpret_cast<uint4*>(&Bs[r1 * 40 + ko1]) = RB1;                               \
    __syncthreads();                                                                   \
    if ((KT) + 2 < 27) {                                                               \
      const int k0n = ((KT) + 2) * 32;                                                 \
      RA0 = *reinterpret_cast<const uint4*>(Ag + (size_t)(m0 + r0) * KPAD + k0n + ko0);\
      RA1 = *reinterpret_cast<const uint4*>(Ag + (size_t)(m0 + r1) * KPAD + k0n + ko1);\
      RB0 = *reinterpret_cast<const uint4*>(Bg + (size_t)r0 * KPAD + k0n + ko0);       \
      RB1 = *reinterpret_cast<const uint4*>(Bg + (size_t)r1 * KPAD + k0n + ko1);       \
    }                                                                                  \
    bf16x8 af[4], bfr[4];                                                              \
    _Pragma("unroll")                                                                  \
    for (int i = 0; i < 4; ++i)                                                        \
      af[i] = *reinterpret_cast<const bf16x8*>(&As[(wm + i * 16 + lr) * 40 + quad * 8]); \
    _Pragma("unroll")                                                                  \
    for (int j = 0; j < 4; ++j)                                                        \
      bfr[j] = *reinterpret_cast<const bf16x8*>(&Bs[(wn + j * 16 + lr) * 40 + quad * 8]); \
    _Pragma("unroll")                                                                  \
    for (int i = 0; i < 4; ++i)                                                        \
      _Pragma("unroll")                                                                \
      for (int j = 0; j < 4; ++j)                                                      \
        acc[i][j] = __builtin_amdgcn_mfma_f32_16x16x32_bf16(af[i], bfr[j], acc[i][j], 0, 0, 0); \
  }

__global__ __launch_bounds__(256, 3) void ctx_mfma(const unsigned short* __restrict__ Ah,
                                                   const unsigned short* __restrict__ BhT,
                                                   const float* __restrict__ b_c,
                                                   unsigned short* __restrict__ ctxT) {
  __shared__ unsigned short As[128 * 40];
  __shared__ unsigned short Bs[128 * 40];
  const int zb = blockIdx.z;
  const int g = zb & 3, b = zb >> 2;        // L2-friendly: adjacent z share b
  const int zout = (g << 4) + b;            // logical z for output layout
  const int n0 = blockIdx.x * 128;
  const int m0 = blockIdx.y * 128;
  const int tid = threadIdx.x;
  const int wave = tid >> 6, lane = tid & 63;
  const int wm = (wave >> 1) * 64, wn = (wave & 1) * 64;
  const int quad = lane >> 4, lr = lane & 15;

  const unsigned short* Ag = BhT + (size_t)b * SS * KPAD;
  const unsigned short* Bg = Ah + (size_t)g * 256 * KPAD + (size_t)n0 * KPAD;

  const int c0 = tid, c1 = tid + 256;
  const int r0 = c0 >> 2, ko0 = (c0 & 3) * 8;
  const int r1 = c1 >> 2, ko1 = (c1 & 3) * 8;

  f32x4 acc[4][4];
  #pragma unroll
  for (int i = 0; i < 4; ++i)
    #pragma unroll
    for (int j = 0; j < 4; ++j) acc[i][j] = (f32x4){0.f, 0.f, 0.f, 0.f};

  uint4 ra0a, ra1a, rb0a, rb1a, ra0b, ra1b, rb0b, rb1b;
  ra0a = *reinterpret_cast<const uint4*>(Ag + (size_t)(m0 + r0) * KPAD + ko0);
  ra1a = *reinterpret_cast<const uint4*>(Ag + (size_t)(m0 + r1) * KPAD + ko1);
  rb0a = *reinterpret_cast<const uint4*>(Bg + (size_t)r0 * KPAD + ko0);
  rb1a = *reinterpret_cast<const uint4*>(Bg + (size_t)r1 * KPAD + ko1);
  ra0b = *reinterpret_cast<const uint4*>(Ag + (size_t)(m0 + r0) * KPAD + 32 + ko0);
  ra1b = *reinterpret_cast<const uint4*>(Ag + (size_t)(m0 + r1) * KPAD + 32 + ko1);
  rb0b = *reinterpret_cast<const uint4*>(Bg + (size_t)r0 * KPAD + 32 + ko0);
  rb1b = *reinterpret_cast<const uint4*>(Bg + (size_t)r1 * KPAD + 32 + ko1);

  for (int kt = 0; kt < 27; kt += 2) {
    CTX_STEP(ra0a, ra1a, rb0a, rb1a, kt);
    if (kt + 1 < 27) CTX_STEP(ra0b, ra1b, rb0b, rb1b, kt + 1);
  }

  unsigned short* Cz = ctxT + (size_t)zout * SPAD * GF;
  const float* bias = b_c + g * GF;
  #pragma unroll
  for (int j = 0; j < 4; ++j) {
    const int n = n0 + wn + j * 16 + lr;
    const float bv = bias[n];
    #pragma unroll
    for (int i = 0; i < 4; ++i) {
      #pragma unroll
      for (int reg = 0; reg < 4; ++reg) {
        const int m = m0 + wm + i * 16 + quad * 4 + reg;
        Cz[(size_t)m * GF + n] = f2bf(acc[i][j][reg] + bv);
      }
    }
  }
}

// ---------------- fused attention: logits MFMA + online softmax + PV ----------------
__global__ __launch_bounds__(256) void att_part(
    const unsigned short* __restrict__ ctxT,
    const unsigned short* __restrict__ emb_h,
    float* __restrict__ Opart,     // [64*8][16][256]
    float* __restrict__ Spart)     // [64*8][32]: 16 M then 16 L
{
  __shared__ unsigned short Cs[4][32 * CROW];
  __shared__ float Ps[4][32][20];
  __shared__ float walpha[4][16];
  __shared__ float wms[4][16], wls[4][16];
  const int sc = blockIdx.x, z = blockIdx.y;
  const int g = z >> 4, b = z & 15;
  const int count = c_counts[b], off = c_offs[b];
  const int t0 = c_t0[sc], t1 = c_t1[sc];
  const int tid = threadIdx.x, wave = tid >> 6, lane = tid & 63;
  const int quad = lane >> 4, lr = lane & 15;
  const unsigned short* Az = ctxT + (size_t)z * SPAD * GF;
  const bool bvalid = (lr < count);
  const unsigned short* Brow = emb_h + (size_t)(off + (bvalid ? lr : 0)) * INDIM + (g << 8);
  unsigned short* myC = &Cs[wave][0];
  const int fbase = quad * 64 + lr * 4;
  const bf16x8 zero8 = (bf16x8)(short)0;

  float O[16][4];
  #pragma unroll
  for (int n = 0; n < 16; ++n)
    #pragma unroll
    for (int j = 0; j < 4; ++j) O[n][j] = 0.f;
  float m_run = -3.0e38f, l_run = 0.f;

  for (int t = t0 + wave; t < t1; t += 4) {
    const int s0 = t * 32;
    #pragma unroll
    for (int q = 0; q < 16; ++q) {
      const int row = 2 * q + (lane >> 5);
      const int col = (lane & 31) * 8;
      const uint4 v = *reinterpret_cast<const uint4*>(Az + (size_t)(s0 + row) * GF + col);
      *reinterpret_cast<uint4*>(&myC[row * CROW + col]) = v;
    }
    f32x4 acc[2] = {(f32x4){0.f,0.f,0.f,0.f}, (f32x4){0.f,0.f,0.f,0.f}};
    #pragma unroll
    for (int kk = 0; kk < 8; ++kk) {
      const int f = kk * 32 + quad * 8;
      bf16x8 bv8 = *reinterpret_cast<const bf16x8*>(Brow + f);
      if (!bvalid) bv8 = zero8;
      #pragma unroll
      for (int i = 0; i < 2; ++i) {
        const bf16x8 av8 = *reinterpret_cast<const bf16x8*>(&myC[(i * 16 + lr) * CROW + f]);
        acc[i] = __builtin_amdgcn_mfma_f32_16x16x32_bf16(av8, bv8, acc[i], 0, 0, 0);
      }
    }
    float mx = acc[0][0];
    #pragma unroll
    for (int i = 0; i < 2; ++i)
      #pragma unroll
      for (int r = 0; r < 4; ++r) mx = fmaxf(mx, acc[i][r]);
    float lsum = 0.f;
    #pragma unroll
    for (int i = 0; i < 2; ++i)
      #pragma unroll
      for (int r = 0; r < 4; ++r) lsum += __expf(acc[i][r] - mx);
    #pragma unroll
    for (int d = 16; d < 64; d <<= 1) {
      const float om = __shfl_xor(mx, d, 64);
      const float ol = __shfl_xor(lsum, d, 64);
      const float M = fmaxf(mx, om);
      lsum = lsum * __expf(mx - M) + ol * __expf(om - M);
      mx = M;
    }
    const float m_new = fmaxf(m_run, mx);
    const float alpha = __expf(m_run - m_new);
    const float beta  = __expf(mx - m_new);
    l_run = alpha * l_run + beta * lsum;
    m_run = m_new;
    if (lane < 16) walpha[wave][lane] = alpha;
    #pragma unroll
    for (int i = 0; i < 2; ++i)
      #pragma unroll
      for (int r = 0; r < 4; ++r) {
        const int sl = i * 16 + quad * 4 + r;
        Ps[wave][sl][lr] = beta * __expf(acc[i][r] - mx);
      }
    float av[16];
    {
      const float4 a0 = *reinterpret_cast<const float4*>(&walpha[wave][0]);
      const float4 a1 = *reinterpret_cast<const float4*>(&walpha[wave][4]);
      const float4 a2 = *reinterpret_cast<const float4*>(&walpha[wave][8]);
      const float4 a3 = *reinterpret_cast<const float4*>(&walpha[wave][12]);
      av[0]=a0.x; av[1]=a0.y; av[2]=a0.z; av[3]=a0.w;
      av[4]=a1.x; av[5]=a1.y; av[6]=a1.z; av[7]=a1.w;
      av[8]=a2.x; av[9]=a2.y; av[10]=a2.z; av[11]=a2.w;
      av[12]=a3.x; av[13]=a3.y; av[14]=a3.z; av[15]=a3.w;
    }
    #pragma unroll
    for (int n = 0; n < 16; ++n)
      #pragma unroll
      for (int j = 0; j < 4; ++j) O[n][j] *= av[n];
    for (int s = 0; s < 32; ++s) {
      const float4 p0 = *reinterpret_cast<const float4*>(&Ps[wave][s][0]);
      const float4 p1 = *reinterpret_cast<const float4*>(&Ps[wave][s][4]);
      const float4 p2 = *reinterpret_cast<const float4*>(&Ps[wave][s][8]);
      const float4 p3 = *reinterpret_cast<const float4*>(&Ps[wave][s][12]);
      const us4 cv = *reinterpret_cast<const us4*>(&myC[s * CROW + fbase]);
      const float c0 = bf2f(cv[0]), c1 = bf2f(cv[1]), c2 = bf2f(cv[2]), c3 = bf2f(cv[3]);
      const float pn[16] = {p0.x,p0.y,p0.z,p0.w, p1.x,p1.y,p1.z,p1.w,
                            p2.x,p2.y,p2.z,p2.w, p3.x,p3.y,p3.z,p3.w};
      #pragma unroll
      for (int n = 0; n < 16; ++n) {
        O[n][0] = fmaf(pn[n], c0, O[n][0]);
        O[n][1] = fmaf(pn[n], c1, O[n][1]);
        O[n][2] = fmaf(pn[n], c2, O[n][2]);
        O[n][3] = fmaf(pn[n], c3, O[n][3]);
      }
    }
  }

  if (lane < 16) { wms[wave][lane] = m_run; wls[wave][lane] = l_run; }
  __syncthreads();
  float* Ob = reinterpret_cast<float*>(&Cs[wave][0]);
  #pragma unroll
  for (int n = 0; n < 16; ++n) {
    const float Mb = fmaxf(fmaxf(wms[0][n], wms[1][n]), fmaxf(wms[2][n], wms[3][n]));
    const float e = __expf(wms[wave][n] - Mb);
    #pragma unroll
    for (int j = 0; j < 4; ++j) Ob[n * 256 + fbase + j] = O[n][j] * e;
  }
  __syncthreads();
  float* Op = Opart + ((size_t)z * 8 + sc) * 4096;
  #pragma unroll
  for (int nn = 0; nn < 4; ++nn) {
    const int n = wave * 4 + nn;
    float4 v = {0.f, 0.f, 0.f, 0.f};
    #pragma unroll
    for (int w = 0; w < 4; ++w) {
      const float4 x = *reinterpret_cast<const float4*>(
          reinterpret_cast<const float*>(&Cs[w][0]) + n * 256 + fbase);
      v.x += x.x; v.y += x.y; v.z += x.z; v.w += x.w;
    }
    *reinterpret_cast<float4*>(Op + n * 256 + fbase) = v;
  }
  if (wave == 0 && lane < 16) {
    const int n = lane;
    const float Mb = fmaxf(fmaxf(wms[0][n], wms[1][n]), fmaxf(wms[2][n], wms[3][n]));
    float Lb = 0.f;
    #pragma unroll
    for (int w = 0; w < 4; ++w) Lb += wls[w][n] * __expf(wms[w][n] - Mb);
    Spart[((size_t)z * 8 + sc) * 32 + n]      = Mb;
    Spart[((size_t)z * 8 + sc) * 32 + 16 + n] = Lb;
  }
}

// combine 8 s-chunk partials -> flat_h = bf16(attn + emb). grid (64 z, 16 n).
__global__ __launch_bounds__(256) void att_combine(
    const float* __restrict__ Opart, const float* __restrict__ Spart,
    const float* __restrict__ emb, unsigned short* __restrict__ flat_h) {
  const int z = blockIdx.x, n = blockIdx.y;
  const int g = z >> 4, b = z & 15;
  const int count = c_counts[b], off = c_offs[b];
  if (n >= count) return;
  const int f = threadIdx.x;
  float M = -3.0e38f;
  #pragma unroll
  for (int sc = 0; sc < 8; ++sc)
    M = fmaxf(M, Spart[((size_t)z * 8 + sc) * 32 + n]);
  float L = 0.f, acc = 0.f;
  #pragma unroll
  for (int sc = 0; sc < 8; ++sc) {
    const float e = __expf(Spart[((size_t)z * 8 + sc) * 32 + n] - M);
    L += e * Spart[((size_t)z * 8 + sc) * 32 + 16 + n];
    acc += e * Opart[((size_t)z * 8 + sc) * 4096 + n * 256 + f];
  }
  const int t = off + n;
  const int col = (g << 8) + f;
  flat_h[t * INDIM + col] = f2bf(acc / L + emb[t * INDIM + col]);
}

// ---------------- head: bf16 MFMA, out = relu(flat_h @ W_h^T) ----------------
__global__ __launch_bounds__(256) void head_mfma(const unsigned short* __restrict__ flat_h,
                                                 const unsigned short* __restrict__ Wh_h,
                                                 float* __restrict__ out) {
  __shared__ unsigned short As[64 * 40];
  __shared__ unsigned short Bs[64 * 40];
  const int g = blockIdx.z;
  const int n0 = blockIdx.x * 64, m0 = blockIdx.y * 64;
  const int tid = threadIdx.x;
  const int wave = tid >> 6, lane = tid & 63;
  const int wm = (wave >> 1) * 32, wn = (wave & 1) * 32;
  const int quad = lane >> 4, lr = lane & 15;
  const int r = tid >> 2, ko = (tid & 3) * 8;

  const unsigned short* Ag = flat_h + (size_t)m0 * INDIM + g * GF;
  const unsigned short* Bg = Wh_h + (size_t)g * GF * GF + (size_t)n0 * GF;

  f32x4 acc[2][2];
  #pragma unroll
  for (int i = 0; i < 2; ++i)
    #pragma unroll
    for (int j = 0; j < 2; ++j) acc[i][j] = (f32x4){0.f, 0.f, 0.f, 0.f};

  const uint4 zero4 = {0u, 0u, 0u, 0u};
  uint4 ra, rb;
  ra = (m0 + r < TOTAL) ? *reinterpret_cast<const uint4*>(Ag + (size_t)r * INDIM + ko) : zero4;
  rb = *reinterpret_cast<const uint4*>(Bg + (size_t)r * GF + ko);

  for (int kt = 0; kt < 8; ++kt) {
    __syncthreads();
    *reinterpret_cast<uint4*>(&As[r * 40 + ko]) = ra;
    *reinterpret_cast<uint4*>(&Bs[r * 40 + ko]) = rb;
    __syncthreads();
    if (kt < 7) {
      const int k0 = (kt + 1) * 32;
      ra = (m0 + r < TOTAL) ? *reinterpret_cast<const uint4*>(Ag + (size_t)r * INDIM + k0 + ko) : zero4;
      rb = *reinterpret_cast<const uint4*>(Bg + (size_t)r * GF + k0 + ko);
    }
    bf16x8 af[2], bfr[2];
    #pragma unroll
    for (int i = 0; i < 2; ++i)
      af[i] = *reinterpret_cast<const bf16x8*>(&As[(wm + i * 16 + lr) * 40 + quad * 8]);
    #pragma unroll
    for (int j = 0; j < 2; ++j)
      bfr[j] = *reinterpret_cast<const bf16x8*>(&Bs[(wn + j * 16 + lr) * 40 + quad * 8]);
    #pragma unroll
    for (int i = 0; i < 2; ++i)
      #pragma unroll
      for (int j = 0; j < 2; ++j)
        acc[i][j] = __builtin_amdgcn_mfma_f32_16x16x32_bf16(af[i], bfr[j], acc[i][j], 0, 0, 0);
  }

  #pragma unroll
  for (int i = 0; i < 2; ++i) {
    #pragma unroll
    for (int reg = 0; reg < 4; ++reg) {
      const int m = m0 + wm + i * 16 + quad * 4 + reg;
      if (m >= TOTAL) continue;
      #pragma unroll
      for (int j = 0; j < 2; ++j) {
        const int n = n0 + wn + j * 16 + lr;
        out[(size_t)m * INDIM + g * GF + n] = fmaxf(acc[i][j][reg], 0.f);
      }
    }
  }
}

extern "C" void kernel_launch(void* const* d_in, const int* in_sizes, int n_in,
                              void* d_out, int out_size, void* d_ws, size_t ws_size,
                              hipStream_t stream) {
  (void)in_sizes; (void)n_in; (void)out_size; (void)ws_size;
  const float* actor = (const float*)d_in[0];
  const float* fmap  = (const float*)d_in[1];
  const float* W_a   = (const float*)d_in[2];
  const float* b_a   = (const float*)d_in[3];
  const float* W_c   = (const float*)d_in[4];
  const float* b_c   = (const float*)d_in[5];
  const float* W_h   = (const float*)d_in[6];
  float* out = (float*)d_out;
  char* ws = (char*)d_ws;

  float* emb             = (float*)(ws);                        // 655,360 B
  unsigned short* flat_h = (unsigned short*)(ws + 655360);      // 327,680 B
  unsigned short* emb_h  = (unsigned short*)(ws + 983040);      // 327,680 B
  float* Spart           = (float*)(ws + 1310720);              // 65,536 B
  unsigned short* ctxT   = (unsigned short*)(ws + 1376256);     // 54,525,952 B
  unsigned short* Ah     = (unsigned short*)(ws + 55902208);    // 1,769,472 B
  unsigned short* BhT    = (unsigned short*)(ws + 57671680);    // 43,352,064 B
  float* Opart           = (float*)(ws + 57671680);             // 33,554,432 B, aliases BhT (time-disjoint)
  unsigned short* Wh_h   = (unsigned short*)(ws + 101023744);   // 524,288 B (end 101,548,032)

  // 0) mega-fused front end: emb MFMA + weight packs + fm transpose
  hipLaunchKernelGGL(prep_all, dim3(24928), dim3(256), 0, stream,
                     actor, W_a, b_a, W_c, W_h, fmap,
                     emb, emb_h, Ah, Wh_h, BhT);

  // 1) ctxT via bf16 MFMA, 128x128 tile, L2-friendly z order
  hipLaunchKernelGGL(ctx_mfma, dim3(2, 13, 64), dim3(256), 0, stream, Ah, BhT, b_c, ctxT);

  // 2) fused attention (logits + online softmax + PV), s-split 8
  hipLaunchKernelGGL(att_part, dim3(8, 64), dim3(256), 0, stream,
                     ctxT, emb_h, Opart, Spart);

  // 3) combine partials -> flat_h = bf16(attn + emb)
  hipLaunchKernelGGL(att_combine, dim3(64, 16), dim3(256), 0, stream,
                     Opart, Spart, emb, flat_h);

  // 4) out = relu(flat_h @ W_h^T)
  hipLaunchKernelGGL(head_mfma, dim3(4, 3, 4), dim3(256), 0, stream,
                     flat_h, Wh_h, out);
}